// Round 1
// baseline (264.615 us; speedup 1.0000x reference)
//
#include <hip/hip_runtime.h>
#include <hip/hip_bf16.h>
#include <cstdint>

#define Q_ 100
#define G_ 16
#define T_ 2
#define H_ 128
#define W_ 128
#define HW_ (H_*W_)
#define C_ 81
#define CH_ 4   // chunks per (q,t) in pairwise kernel

__device__ __forceinline__ float sp_(float z) {
    // softplus log(1+exp(z)), stable
    return fmaxf(z, 0.0f) + __logf(1.0f + __expf(-fabsf(z)));
}
__device__ __forceinline__ float lae_(float a, float b) {
    // logaddexp
    return fmaxf(a, b) + __logf(1.0f + __expf(-fabsf(a - b)));
}

__device__ __forceinline__ float waveSum_(float v) {
    #pragma unroll
    for (int o = 32; o > 0; o >>= 1) v += __shfl_down(v, o, 64);
    return v;
}

// ---------------- kernel A: class cost (initializes out) ----------------
__global__ void k_class(const float* __restrict__ logits,
                        const int* __restrict__ ids,
                        float* __restrict__ out) {
    int q = blockIdx.x;
    int tid = threadIdx.x; // 128 threads, 2 waves
    __shared__ float wred[2];

    float v = (tid < C_) ? logits[q * C_ + tid] : -INFINITY;
    float m = v;
    #pragma unroll
    for (int o = 32; o > 0; o >>= 1) m = fmaxf(m, __shfl_down(m, o, 64));
    if ((tid & 63) == 0) wred[tid >> 6] = m;
    __syncthreads();
    float bmax = fmaxf(wred[0], wred[1]);
    __syncthreads();

    float e = (tid < C_) ? __expf(v - bmax) : 0.0f;
    float s = waveSum_(e);
    if ((tid & 63) == 0) wred[tid >> 6] = s;
    __syncthreads();
    float tot = wred[0] + wred[1];

    if (tid < G_) {
        int id = ids[tid];
        float p = __expf(logits[q * C_ + id] - bmax) / tot;
        out[q * G_ + tid] = -p;
    }
}

// ---------------- kernel B: src projection maxes ----------------
__global__ void k_srcmax(const float* __restrict__ om,
                         float* __restrict__ srcMW,   // (Q*T, H)  max over W
                         float* __restrict__ srcMH) { // (Q*T, W)  max over H
    int qt = blockIdx.x;               // 0..Q*T-1
    int tid = threadIdx.x;             // 128
    const float* base = om + (size_t)qt * HW_;

    // max over h (coalesced): thread = w
    float m = -INFINITY;
    for (int h = 0; h < H_; ++h) m = fmaxf(m, base[h * W_ + tid]);
    srcMH[qt * W_ + tid] = 1.0f / (1.0f + __expf(-m));

    // max over w: thread = h
    float r = -INFINITY;
    const float* row = base + tid * W_;
    for (int w = 0; w < W_; ++w) r = fmaxf(r, row[w]);
    srcMW[qt * H_ + tid] = 1.0f / (1.0f + __expf(-r));
}

__global__ void k_tgtmax(const int* __restrict__ box,
                         float* __restrict__ tgtMW,   // (G*T, H)
                         float* __restrict__ tgtMH) { // (G*T, W)
    int gt = blockIdx.x;               // 0..G*T-1
    int tid = threadIdx.x;             // 128
    const int* base = box + (size_t)gt * HW_;

    int m = 0;
    for (int h = 0; h < H_; ++h) m = max(m, base[h * W_ + tid]);
    tgtMH[gt * W_ + tid] = (float)m;

    int r = 0;
    const int* row = base + tid * W_;
    for (int w = 0; w < W_; ++w) r = max(r, row[w]);
    tgtMW[gt * H_ + tid] = (float)r;
}

// ---------------- kernel C: dice on projections, out += ----------------
__device__ __forceinline__ float blockSum256_(float v, float* lds) {
    v = waveSum_(v);
    int wid = threadIdx.x >> 6;
    if ((threadIdx.x & 63) == 0) lds[wid] = v;
    __syncthreads();
    float r = lds[0] + lds[1] + lds[2] + lds[3];
    __syncthreads();
    return r;
}

__global__ void k_dice(const float* __restrict__ srcMW, const float* __restrict__ srcMH,
                       const float* __restrict__ tgtMW, const float* __restrict__ tgtMH,
                       float* __restrict__ out) {
    int q = blockIdx.x;
    int c = threadIdx.x;  // 256 = T*128, flattened (t, h) / (t, w)
    __shared__ float lds[4];

    float sW = srcMW[q * 256 + c];
    float sH = srcMH[q * 256 + c];
    float Ss3 = blockSum256_(sW, lds);
    float Ss2 = blockSum256_(sH, lds);

    for (int g = 0; g < G_; ++g) {
        float tW = tgtMW[g * 256 + c];
        float tH = tgtMH[g * 256 + c];
        float d3 = blockSum256_(sW * tW, lds);
        float t3 = blockSum256_(tW, lds);
        float d2 = blockSum256_(sH * tH, lds);
        float t2 = blockSum256_(tH, lds);
        if (threadIdx.x == 0) {
            float dice3 = 1.0f - (2.0f * d3 + 1.0f) / (Ss3 + t3 + 1.0f);
            float dice2 = 1.0f - (2.0f * d2 + 1.0f) / (Ss2 + t2 + 1.0f);
            out[q * G_ + g] += dice3 + dice2;
        }
    }
}

// ---------------- kernel D: pack tgt bits ----------------
__global__ void k_pack(const float* __restrict__ sims,
                       const int* __restrict__ box,
                       uint4* __restrict__ packed) {
    int p = blockIdx.x * 256 + threadIdx.x;  // 0..T*HW-1
    int t = p / HW_, pp = p % HW_;
    unsigned w[4] = {0u, 0u, 0u, 0u};
    #pragma unroll
    for (int g = 0; g < G_; ++g) {
        int b = box[(size_t)(g * T_ + t) * HW_ + pp];
        unsigned byte = 0u;
        #pragma unroll
        for (int e = 0; e < 8; ++e) {
            float sv = sims[((size_t)(g * T_ + t) * 8 + e) * HW_ + pp];
            byte |= (sv >= 0.3f ? 1u : 0u) << e;
        }
        byte = b ? byte : 0u;
        w[g >> 2] |= byte << ((g & 3) * 8);
    }
    packed[p] = make_uint4(w[0], w[1], w[2], w[3]);
}

// ---------------- kernel D2: denominators ----------------
__global__ void k_denom(const uint4* __restrict__ packed,
                        float* __restrict__ rdenom) {
    int g = blockIdx.x & (G_ - 1);
    int t = blockIdx.x >> 4;
    __shared__ float lds[4];
    int cnt = 0;
    for (int p = threadIdx.x; p < HW_; p += 256) {
        uint4 v = packed[t * HW_ + p];
        unsigned word = (g < 4) ? v.x : (g < 8) ? v.y : (g < 12) ? v.z : v.w;
        unsigned byte = (word >> ((g & 3) * 8)) & 0xffu;
        cnt += __popc(byte);
    }
    float tot = blockSum256_((float)cnt, lds);
    if (threadIdx.x == 0) rdenom[g * T_ + t] = 0.5f / fmaxf(1.0f, tot);
}

// ---------------- kernel E: pairwise main ----------------
__launch_bounds__(256)
__global__ void k_pair(const float* __restrict__ om,
                       const uint4* __restrict__ packed,
                       const float* __restrict__ rdenom,
                       float* __restrict__ out) {
    int bid = blockIdx.x;           // (q*T + t)*CH + ch
    int ch = bid & (CH_ - 1);
    int qt = bid / CH_;
    int t = qt & (T_ - 1);
    int q = qt / T_;
    const float* base = om + (size_t)qt * HW_;
    const uint4* pk = packed + (size_t)t * HW_;

    float acc[G_];
    #pragma unroll
    for (int g = 0; g < G_; ++g) acc[g] = 0.0f;

    const int pixPerChunk = HW_ / CH_;
    int pEnd = (ch + 1) * pixPerChunk;
    for (int p = ch * pixPerChunk + threadIdx.x; p < pEnd; p += 256) {
        int h = p >> 7, w = p & (W_ - 1);
        float x = base[p];
        float lf = -sp_(-x);
        float lb = -sp_(x);

        const int dy[8] = {-2, -2, -2,  0, 0,  2, 2, 2};
        const int dx[8] = {-2,  0,  2, -2, 2, -2, 0, 2};
        float s[8];
        #pragma unroll
        for (int e = 0; e < 8; ++e) {
            int hn = h + dy[e], wn = w + dx[e];
            float se = 0.0f;
            if ((unsigned)hn < (unsigned)H_ && (unsigned)wn < (unsigned)W_) {
                float xn = base[hn * W_ + wn];
                float lfn = -sp_(-xn);
                float lbn = -sp_(xn);
                se = -lae_(lf + lfn, lb + lbn);
            }
            s[e] = se;
        }

        uint4 v = pk[p];
        unsigned wd[4] = {v.x, v.y, v.z, v.w};
        #pragma unroll
        for (int g = 0; g < G_; ++g) {
            unsigned byte = (wd[g >> 2] >> ((g & 3) * 8)) & 0xffu;
            float sum = 0.0f;
            #pragma unroll
            for (int e = 0; e < 8; ++e) sum += ((byte >> e) & 1u) ? s[e] : 0.0f;
            acc[g] += sum;
        }
    }

    __shared__ float lds[4][G_];
    #pragma unroll
    for (int g = 0; g < G_; ++g) {
        float v = waveSum_(acc[g]);
        if ((threadIdx.x & 63) == 0) lds[threadIdx.x >> 6][g] = v;
    }
    __syncthreads();
    if (threadIdx.x < G_) {
        int g = threadIdx.x;
        float tot = lds[0][g] + lds[1][g] + lds[2][g] + lds[3][g];
        atomicAdd(&out[q * G_ + g], tot * rdenom[g * T_ + t]);
    }
}

extern "C" void kernel_launch(void* const* d_in, const int* in_sizes, int n_in,
                              void* d_out, int out_size, void* d_ws, size_t ws_size,
                              hipStream_t stream) {
    const float* pred_logits = (const float*)d_in[0];
    const float* out_mask    = (const float*)d_in[1];
    const float* sims        = (const float*)d_in[2];
    const int*   tgt_ids     = (const int*)d_in[3];
    const int*   tgt_box     = (const int*)d_in[4];
    float* out = (float*)d_out;

    // workspace layout
    float* srcMW  = (float*)d_ws;                 // Q*T*H = 25600
    float* srcMH  = srcMW + Q_ * T_ * H_;         // 25600
    float* tgtMW  = srcMH + Q_ * T_ * W_;         // 4096
    float* tgtMH  = tgtMW + G_ * T_ * H_;         // 4096
    float* rdenom = tgtMH + G_ * T_ * W_;         // 32
    uintptr_t pk_addr = ((uintptr_t)(rdenom + G_ * T_) + 255) & ~(uintptr_t)255;
    uint4* packed = (uint4*)pk_addr;              // T*HW uint4 = 512 KB

    k_class<<<Q_, 128, 0, stream>>>(pred_logits, tgt_ids, out);
    k_srcmax<<<Q_ * T_, 128, 0, stream>>>(out_mask, srcMW, srcMH);
    k_tgtmax<<<G_ * T_, 128, 0, stream>>>(tgt_box, tgtMW, tgtMH);
    k_dice<<<Q_, 256, 0, stream>>>(srcMW, srcMH, tgtMW, tgtMH, out);
    k_pack<<<(T_ * HW_) / 256, 256, 0, stream>>>(sims, tgt_box, packed);
    k_denom<<<G_ * T_, 256, 0, stream>>>(packed, rdenom);
    k_pair<<<Q_ * T_ * CH_, 256, 0, stream>>>(out_mask, packed, rdenom, out);
}

// Round 2
// 150.869 us; speedup vs baseline: 1.7539x; 1.7539x over previous
//
#include <hip/hip_runtime.h>
#include <cstdint>

#define Q_ 100
#define G_ 16
#define T_ 2
#define H_ 128
#define W_ 128
#define HW_ (H_*W_)
#define C_ 81
#define ROWS_ 8   // output rows per k_pair block (halo +2 each side)

__device__ __forceinline__ float sp_(float z) {
    // softplus log(1+exp(z)), stable
    return fmaxf(z, 0.0f) + __logf(1.0f + __expf(-fabsf(z)));
}
__device__ __forceinline__ float sig_(float x) { return 1.0f / (1.0f + __expf(-x)); }

__device__ __forceinline__ float waveSumF_(float v) {
    #pragma unroll
    for (int o = 32; o > 0; o >>= 1) v += __shfl_down(v, o, 64);
    return v;
}
__device__ __forceinline__ int waveSumI_(int v) {
    #pragma unroll
    for (int o = 32; o > 0; o >>= 1) v += __shfl_down(v, o, 64);
    return v;
}

// ---------------- kernel A: class cost (initializes out) + zero cnt ----------------
__global__ void k_class(const float* __restrict__ logits,
                        const int* __restrict__ ids,
                        float* __restrict__ out,
                        int* __restrict__ cnt) {
    int q = blockIdx.x;
    int tid = threadIdx.x; // 128 threads, 2 waves
    __shared__ float wred[2];

    if (q == 0 && tid < G_ * T_) cnt[tid] = 0;   // zero pair-denominator counts

    float v = (tid < C_) ? logits[q * C_ + tid] : -INFINITY;
    float m = v;
    #pragma unroll
    for (int o = 32; o > 0; o >>= 1) m = fmaxf(m, __shfl_down(m, o, 64));
    if ((tid & 63) == 0) wred[tid >> 6] = m;
    __syncthreads();
    float bmax = fmaxf(wred[0], wred[1]);
    __syncthreads();

    float e = (tid < C_) ? __expf(v - bmax) : 0.0f;
    float s = waveSumF_(e);
    if ((tid & 63) == 0) wred[tid >> 6] = s;
    __syncthreads();
    float tot = wred[0] + wred[1];

    if (tid < G_) {
        int id = ids[tid];
        float p = __expf(logits[q * C_ + id] - bmax) / tot;
        out[q * G_ + tid] = -p;
    }
}

// ---------------- kernel B: src projection maxes (vectorized) ----------------
__launch_bounds__(256)
__global__ void k_srcmax(const float* __restrict__ om,
                         float* __restrict__ srcMW,   // (Q*T, H)  sigmoid(max over W)
                         float* __restrict__ srcMH) { // (Q*T, W)  sigmoid(max over H)
    int qt = blockIdx.x;
    int tid = threadIdx.x;
    const float* base = om + (size_t)qt * HW_;

    // row max: thread pair (r, half) each scans 64 cols via float4
    {
        int r = tid >> 1;
        const float4* rp = (const float4*)(base + r * W_ + (tid & 1) * 64);
        float m = -1e30f;
        #pragma unroll
        for (int i = 0; i < 16; ++i) {
            float4 v = rp[i];
            m = fmaxf(m, fmaxf(fmaxf(v.x, v.y), fmaxf(v.z, v.w)));
        }
        m = fmaxf(m, __shfl_xor(m, 1, 64));
        if (!(tid & 1)) srcMW[qt * H_ + r] = sig_(m);
    }
    // col max: thread (c4, rowgroup) scans 16 rows of a 4-col strip
    __shared__ float4 part[8][32];
    {
        int c4 = tid & 31, rgp = tid >> 5;
        const float* cp = base + rgp * 16 * W_ + c4 * 4;
        float4 m = make_float4(-1e30f, -1e30f, -1e30f, -1e30f);
        #pragma unroll
        for (int i = 0; i < 16; ++i) {
            float4 v = *(const float4*)(cp + (size_t)i * W_);
            m.x = fmaxf(m.x, v.x); m.y = fmaxf(m.y, v.y);
            m.z = fmaxf(m.z, v.z); m.w = fmaxf(m.w, v.w);
        }
        part[rgp][c4] = m;
    }
    __syncthreads();
    if (tid < 32) {
        float4 m = part[0][tid];
        #pragma unroll
        for (int r = 1; r < 8; ++r) {
            float4 v = part[r][tid];
            m.x = fmaxf(m.x, v.x); m.y = fmaxf(m.y, v.y);
            m.z = fmaxf(m.z, v.z); m.w = fmaxf(m.w, v.w);
        }
        float* o = srcMH + qt * W_ + tid * 4;
        o[0] = sig_(m.x); o[1] = sig_(m.y); o[2] = sig_(m.z); o[3] = sig_(m.w);
    }
}

__launch_bounds__(256)
__global__ void k_tgtmax(const int* __restrict__ box,
                         float* __restrict__ tgtMW,   // (G*T, H)
                         float* __restrict__ tgtMH) { // (G*T, W)
    int gt = blockIdx.x;
    int tid = threadIdx.x;
    const int* base = box + (size_t)gt * HW_;

    {
        int r = tid >> 1;
        const int4* rp = (const int4*)(base + r * W_ + (tid & 1) * 64);
        int m = 0;
        #pragma unroll
        for (int i = 0; i < 16; ++i) {
            int4 v = rp[i];
            m = max(m, max(max(v.x, v.y), max(v.z, v.w)));
        }
        m = max(m, __shfl_xor(m, 1, 64));
        if (!(tid & 1)) tgtMW[gt * H_ + r] = (float)m;
    }
    __shared__ int4 parti[8][32];
    {
        int c4 = tid & 31, rgp = tid >> 5;
        const int* cp = base + rgp * 16 * W_ + c4 * 4;
        int4 m = make_int4(0, 0, 0, 0);
        #pragma unroll
        for (int i = 0; i < 16; ++i) {
            int4 v = *(const int4*)(cp + (size_t)i * W_);
            m.x = max(m.x, v.x); m.y = max(m.y, v.y);
            m.z = max(m.z, v.z); m.w = max(m.w, v.w);
        }
        parti[rgp][c4] = m;
    }
    __syncthreads();
    if (tid < 32) {
        int4 m = parti[0][tid];
        #pragma unroll
        for (int r = 1; r < 8; ++r) {
            int4 v = parti[r][tid];
            m.x = max(m.x, v.x); m.y = max(m.y, v.y);
            m.z = max(m.z, v.z); m.w = max(m.w, v.w);
        }
        float* o = tgtMH + gt * W_ + tid * 4;
        o[0] = (float)m.x; o[1] = (float)m.y; o[2] = (float)m.z; o[3] = (float)m.w;
    }
}

// ---------------- kernel C: dice on projections, one wave per (q,g) ----------------
__global__ void k_dice(const float* __restrict__ srcMW, const float* __restrict__ srcMH,
                       const float* __restrict__ tgtMW, const float* __restrict__ tgtMH,
                       float* __restrict__ out) {
    int q = blockIdx.x >> 4;
    int g = blockIdx.x & 15;
    int l = threadIdx.x;  // 64
    float d3 = 0, t3 = 0, s3 = 0, d2 = 0, t2 = 0, s2 = 0;
    #pragma unroll
    for (int i = 0; i < 4; ++i) {
        int c = l + i * 64;
        float sW = srcMW[q * 256 + c], tW = tgtMW[g * 256 + c];
        float sH = srcMH[q * 256 + c], tH = tgtMH[g * 256 + c];
        d3 += sW * tW; t3 += tW; s3 += sW;
        d2 += sH * tH; t2 += tH; s2 += sH;
    }
    d3 = waveSumF_(d3); t3 = waveSumF_(t3); s3 = waveSumF_(s3);
    d2 = waveSumF_(d2); t2 = waveSumF_(t2); s2 = waveSumF_(s2);
    if (l == 0) {
        float dice3 = 1.0f - (2.0f * d3 + 1.0f) / (s3 + t3 + 1.0f);
        float dice2 = 1.0f - (2.0f * d2 + 1.0f) / (s2 + t2 + 1.0f);
        out[q * G_ + g] += dice3 + dice2;
    }
}

// ---------------- kernel D: pack tgt bits (4 g's per block-group) + popcount ----------------
__launch_bounds__(256)
__global__ void k_pack(const float* __restrict__ sims,
                       const int* __restrict__ box,
                       uint32_t* __restrict__ packed,   // [4][T*HW] words (4 g's per word)
                       int* __restrict__ cnt) {         // [T][G]
    int bid = blockIdx.x;
    int gg = bid & 3;
    int p = (bid >> 2) * 256 + threadIdx.x;  // 0..T*HW-1
    int t = p >> 14;
    int pp = p & (HW_ - 1);
    uint32_t word = 0;
    int pc[4];
    #pragma unroll
    for (int b = 0; b < 4; ++b) {
        int g = gg * 4 + b;
        int bx = box[(size_t)(g * T_ + t) * HW_ + pp];
        uint32_t byte = 0;
        #pragma unroll
        for (int e = 0; e < 8; ++e) {
            float sv = sims[((size_t)(g * T_ + t) * 8 + e) * HW_ + pp];
            byte |= (sv >= 0.3f ? 1u : 0u) << e;
        }
        byte = bx ? byte : 0u;
        word |= byte << (b * 8);
        pc[b] = __popc(byte);
    }
    packed[gg * (T_ * HW_) + p] = word;

    __shared__ int redI[4][4];
    int wid = threadIdx.x >> 6, lane = threadIdx.x & 63;
    #pragma unroll
    for (int b = 0; b < 4; ++b) {
        int s = waveSumI_(pc[b]);
        if (lane == 0) redI[wid][b] = s;
    }
    __syncthreads();
    if (threadIdx.x < 4) {
        int b = threadIdx.x;
        int tot = redI[0][b] + redI[1][b] + redI[2][b] + redI[3][b];
        atomicAdd(&cnt[t * G_ + gg * 4 + b], tot);
    }
}

// ---------------- kernel E: pairwise main (LDS-staged, softplus refactor) ----------------
__launch_bounds__(256)
__global__ void k_pair(const float* __restrict__ om,
                       const uint32_t* __restrict__ packed,
                       const int* __restrict__ cnt,
                       float* __restrict__ out) {
    int bid = blockIdx.x;        // (q*T + t)*16 + rowgroup
    int rg = bid & 15;
    int qt = bid >> 4;
    int t = qt & 1;
    int q = qt >> 1;
    int rowbase = rg * ROWS_;
    const float* base = om + (size_t)qt * HW_;
    int tid = threadIdx.x;

    __shared__ float2 tile[ROWS_ + 4][W_];   // (x, sp(-x)), rows rowbase-2 .. rowbase+9
    __shared__ float red[4][G_];

    #pragma unroll
    for (int i = 0; i < 6; ++i) {
        int idx = i * 256 + tid;
        int lr = idx >> 7, c = idx & 127;
        int gr = rowbase - 2 + lr;
        float x = ((unsigned)gr < (unsigned)H_) ? base[gr * W_ + c] : 0.0f;
        tile[lr][c] = make_float2(x, sp_(-x));
    }
    __syncthreads();

    const int dy[8] = {-2, -2, -2,  0, 0,  2, 2, 2};
    const int dx[8] = {-2,  0,  2, -2, 2, -2, 0, 2};

    float acc[G_];
    #pragma unroll
    for (int g = 0; g < G_; ++g) acc[g] = 0.0f;

    #pragma unroll
    for (int i = 0; i < 4; ++i) {
        int idx = i * 256 + tid;
        int rr = idx >> 7;          // 0..7
        int c = idx & 127;
        int lr = rr + 2;
        int gr = rowbase + rr;
        float2 self = tile[lr][c];

        float s[8];
        #pragma unroll
        for (int e = 0; e < 8; ++e) {
            int wn = c + dx[e];
            int grn = gr + dy[e];
            float2 nb = tile[lr + dy[e]][wn & 127];
            // -logaddexp(lf+lfn, lb+lbn) == sp(-x) + sp(-xn) - sp(-(x+xn))
            float se = self.y + nb.y - sp_(-(self.x + nb.x));
            bool ok = ((unsigned)wn < (unsigned)W_) && ((unsigned)grn < (unsigned)H_);
            s[e] = ok ? se : 0.0f;
        }

        int pidx = t * HW_ + gr * W_ + c;
        uint32_t wd[4];
        wd[0] = packed[0 * (T_ * HW_) + pidx];
        wd[1] = packed[1 * (T_ * HW_) + pidx];
        wd[2] = packed[2 * (T_ * HW_) + pidx];
        wd[3] = packed[3 * (T_ * HW_) + pidx];
        #pragma unroll
        for (int gg = 0; gg < 4; ++gg) {
            uint32_t w = wd[gg];
            #pragma unroll
            for (int b = 0; b < 4; ++b) {
                uint32_t byte = (w >> (b * 8)) & 255u;
                float sum = 0.0f;
                #pragma unroll
                for (int e = 0; e < 8; ++e) sum += ((byte >> e) & 1u) ? s[e] : 0.0f;
                acc[gg * 4 + b] += sum;
            }
        }
    }

    int wid = tid >> 6, lane = tid & 63;
    #pragma unroll
    for (int g = 0; g < G_; ++g) {
        float v = waveSumF_(acc[g]);
        if (lane == 0) red[wid][g] = v;
    }
    __syncthreads();
    if (tid < G_) {
        int g = tid;
        float tot = red[0][g] + red[1][g] + red[2][g] + red[3][g];
        int den = max(1, cnt[t * G_ + g]);
        atomicAdd(&out[q * G_ + g], tot * (0.5f / (float)den));
    }
}

extern "C" void kernel_launch(void* const* d_in, const int* in_sizes, int n_in,
                              void* d_out, int out_size, void* d_ws, size_t ws_size,
                              hipStream_t stream) {
    const float* pred_logits = (const float*)d_in[0];
    const float* out_mask    = (const float*)d_in[1];
    const float* sims        = (const float*)d_in[2];
    const int*   tgt_ids     = (const int*)d_in[3];
    const int*   tgt_box     = (const int*)d_in[4];
    float* out = (float*)d_out;

    // workspace layout
    float* srcMW  = (float*)d_ws;                 // Q*T*H = 25600
    float* srcMH  = srcMW + Q_ * T_ * H_;         // 25600
    float* tgtMW  = srcMH + Q_ * T_ * W_;         // 4096
    float* tgtMH  = tgtMW + G_ * T_ * H_;         // 4096
    int*   cnt    = (int*)(tgtMH + G_ * T_ * W_); // 32 ints
    uintptr_t pk_addr = ((uintptr_t)(cnt + G_ * T_) + 255) & ~(uintptr_t)255;
    uint32_t* packed = (uint32_t*)pk_addr;        // 4 * T*HW uint32 = 512 KB

    k_class<<<Q_, 128, 0, stream>>>(pred_logits, tgt_ids, out, cnt);
    k_srcmax<<<Q_ * T_, 256, 0, stream>>>(out_mask, srcMW, srcMH);
    k_tgtmax<<<G_ * T_, 256, 0, stream>>>(tgt_box, tgtMW, tgtMH);
    k_dice<<<Q_ * G_, 64, 0, stream>>>(srcMW, srcMH, tgtMW, tgtMH, out);
    k_pack<<<(T_ * HW_ / 256) * 4, 256, 0, stream>>>(sims, tgt_box, packed, cnt);
    k_pair<<<Q_ * T_ * (H_ / ROWS_), 256, 0, stream>>>(out_mask, packed, cnt, out);
}

// Round 4
// 142.415 us; speedup vs baseline: 1.8581x; 1.0594x over previous
//
#include <hip/hip_runtime.h>
#include <hip/hip_fp16.h>
#include <cstdint>

#define Q_ 100
#define G_ 16
#define T_ 2
#define H_ 128
#define W_ 128
#define HW_ (H_*W_)
#define C_ 81

typedef _Float16 half8 __attribute__((ext_vector_type(8)));
typedef float floatx4 __attribute__((ext_vector_type(4)));

__device__ __forceinline__ float sp_(float z) {
    // softplus log(1+exp(z)), stable
    return fmaxf(z, 0.0f) + __logf(1.0f + __expf(-fabsf(z)));
}
__device__ __forceinline__ float sig_(float x) { return 1.0f / (1.0f + __expf(-x)); }

__device__ __forceinline__ float dec_(unsigned u) {
    unsigned b = (u & 0x80000000u) ? (u & 0x7fffffffu) : ~u;
    return __uint_as_float(b);
}

// ---------------- zero the atomic-reduce targets (replaces hipMemsetAsync) ----------------
__global__ void k_zero(unsigned* __restrict__ p, int n) {
    int i = blockIdx.x * 256 + threadIdx.x;
    if (i < n) p[i] = 0u;
}

// ---------------- src projection maxes: (qt, 32-row group) ----------------
__launch_bounds__(256)
__global__ void k_srcmax(const float* __restrict__ om,
                         float* __restrict__ srcMW,       // (QT,128) raw row-max (direct)
                         unsigned* __restrict__ srcMHu) { // (QT,128) encoded col-max (atomic)
    int qt = blockIdx.x >> 2;
    int rg = blockIdx.x & 3;
    const float* base = om + (size_t)qt * HW_ + rg * 32 * W_;
    int tid = threadIdx.x;

    // row max: r = tid>>3 (32 rows), seg = tid&7 (16 floats each)
    {
        int r = tid >> 3, seg = tid & 7;
        const float4* rp = (const float4*)(base + r * W_ + seg * 16);
        float m = -1e30f;
        #pragma unroll
        for (int i = 0; i < 4; ++i) {
            float4 v = rp[i];
            m = fmaxf(m, fmaxf(fmaxf(v.x, v.y), fmaxf(v.z, v.w)));
        }
        m = fmaxf(m, __shfl_xor(m, 1, 64));
        m = fmaxf(m, __shfl_xor(m, 2, 64));
        m = fmaxf(m, __shfl_xor(m, 4, 64));
        if (seg == 0) srcMW[qt * 128 + rg * 32 + r] = m;
    }
    // col max: c = tid&127, rh = tid>>7 (16 rows each)
    __shared__ float cred[128];
    {
        int c = tid & 127, rh = tid >> 7;
        const float* cp = base + rh * 16 * W_ + c;
        float m = -1e30f;
        #pragma unroll
        for (int i = 0; i < 16; ++i) m = fmaxf(m, cp[i * W_]);
        if (rh == 1) cred[c] = m;
        __syncthreads();
        if (rh == 0) {
            m = fmaxf(m, cred[c]);
            unsigned b = __float_as_uint(m);
            unsigned enc = (b & 0x80000000u) ? ~b : (b | 0x80000000u);
            atomicMax(&srcMHu[qt * 128 + c], enc);
        }
    }
}

// ---------------- tgt projection maxes: (gt, 16-row group) ----------------
__launch_bounds__(256)
__global__ void k_tgtmax(const int* __restrict__ box,
                         int* __restrict__ tgtMWi,   // (GT,128) row-max (direct)
                         int* __restrict__ tgtMHi) { // (GT,128) col-max (atomic, zeroed)
    int gt = blockIdx.x >> 3;
    int rg = blockIdx.x & 7;
    const int* base = box + (size_t)gt * HW_ + rg * 16 * W_;
    int tid = threadIdx.x;
    {
        int r = tid >> 4, seg = tid & 15;
        const int4* rp = (const int4*)(base + r * W_ + seg * 8);
        int4 a = rp[0], b = rp[1];
        int m = max(max(max(a.x, a.y), max(a.z, a.w)),
                    max(max(b.x, b.y), max(b.z, b.w)));
        m = max(m, __shfl_xor(m, 1, 64));
        m = max(m, __shfl_xor(m, 2, 64));
        m = max(m, __shfl_xor(m, 4, 64));
        m = max(m, __shfl_xor(m, 8, 64));
        if (seg == 0) tgtMWi[gt * 128 + rg * 16 + r] = m;
    }
    __shared__ int credi[128];
    {
        int c = tid & 127, rh = tid >> 7;
        const int* cp = base + rh * 8 * W_ + c;
        int m = 0;
        #pragma unroll
        for (int i = 0; i < 8; ++i) m = max(m, cp[i * W_]);
        if (rh == 1) credi[c] = m;
        __syncthreads();
        if (rh == 0) {
            m = max(m, credi[c]);
            if (m) atomicMax(&tgtMHi[gt * 128 + c], m);
        }
    }
}

// ---------------- pack tgt bits (byte per g, u32 per (pixel,gg)) + counts ----------------
__launch_bounds__(256)
__global__ void k_pack(const float* __restrict__ sims,
                       const int* __restrict__ box,
                       uint32_t* __restrict__ packed,   // [T*HW][4] u32
                       int* __restrict__ cnt) {         // [T][G] (zeroed)
    int bid = blockIdx.x;
    int gg = bid & 3;
    int p = (bid >> 2) * 256 + threadIdx.x;  // 0..T*HW-1
    int t = p >> 14;
    int pp = p & (HW_ - 1);
    uint32_t word = 0;
    int pc[4];
    #pragma unroll
    for (int b = 0; b < 4; ++b) {
        int g = gg * 4 + b;
        int bx = box[(size_t)(g * T_ + t) * HW_ + pp];
        uint32_t byte = 0;
        #pragma unroll
        for (int e = 0; e < 8; ++e) {
            float sv = sims[((size_t)(g * T_ + t) * 8 + e) * HW_ + pp];
            byte |= (sv >= 0.3f ? 1u : 0u) << e;
        }
        byte = bx ? byte : 0u;
        word |= byte << (b * 8);
        pc[b] = __popc(byte);
    }
    packed[(size_t)p * 4 + gg] = word;

    __shared__ int redI[4][4];
    int wid = threadIdx.x >> 6, lane = threadIdx.x & 63;
    #pragma unroll
    for (int b = 0; b < 4; ++b) {
        int s = pc[b];
        #pragma unroll
        for (int o = 32; o > 0; o >>= 1) s += __shfl_down(s, o, 64);
        if (lane == 0) redI[wid][b] = s;
    }
    __syncthreads();
    if (threadIdx.x < 4) {
        int b = threadIdx.x;
        int tot = redI[0][b] + redI[1][b] + redI[2][b] + redI[3][b];
        atomicAdd(&cnt[t * G_ + gg * 4 + b], tot);
    }
}

// ---------------- dice on projections + class cost; one wave per (q,g) ----------------
__global__ void k_dice(const float* __restrict__ logits, const int* __restrict__ ids,
                       const float* __restrict__ srcMW, const unsigned* __restrict__ srcMHu,
                       const int* __restrict__ tgtMWi, const int* __restrict__ tgtMHi,
                       float* __restrict__ out) {
    int q = blockIdx.x >> 4;
    int g = blockIdx.x & 15;
    int l = threadIdx.x;  // 64

    // softmax over 81 logits
    float v0 = (l < C_) ? logits[q * C_ + l] : -1e30f;
    float v1 = (l + 64 < C_) ? logits[q * C_ + l + 64] : -1e30f;
    float mx = fmaxf(v0, v1);
    #pragma unroll
    for (int o = 32; o > 0; o >>= 1) mx = fmaxf(mx, __shfl_xor(mx, o, 64));
    float es = ((l < C_) ? __expf(v0 - mx) : 0.0f)
             + ((l + 64 < C_) ? __expf(v1 - mx) : 0.0f);
    #pragma unroll
    for (int o = 32; o > 0; o >>= 1) es += __shfl_xor(es, o, 64);

    float d3 = 0, t3 = 0, s3 = 0, d2 = 0, t2 = 0, s2 = 0;
    #pragma unroll
    for (int i = 0; i < 4; ++i) {
        int c = i * 64 + l;   // (t,h)/(t,w) flattened, 256
        float sW = sig_(srcMW[q * 256 + c]);
        float sH = sig_(dec_(srcMHu[q * 256 + c]));
        float tW = (float)tgtMWi[g * 256 + c];
        float tH = (float)tgtMHi[g * 256 + c];
        d3 += sW * tW; t3 += tW; s3 += sW;
        d2 += sH * tH; t2 += tH; s2 += sH;
    }
    #pragma unroll
    for (int o = 32; o > 0; o >>= 1) {
        d3 += __shfl_xor(d3, o, 64); t3 += __shfl_xor(t3, o, 64);
        s3 += __shfl_xor(s3, o, 64); d2 += __shfl_xor(d2, o, 64);
        t2 += __shfl_xor(t2, o, 64); s2 += __shfl_xor(s2, o, 64);
    }
    if (l == 0) {
        float p = __expf(logits[q * C_ + ids[g]] - mx) / es;
        float dice3 = 1.0f - (2.0f * d3 + 1.0f) / (s3 + t3 + 1.0f);
        float dice2 = 1.0f - (2.0f * d2 + 1.0f) / (s2 + t2 + 1.0f);
        out[q * G_ + g] = -p + dice3 + dice2;
    }
}

// ---------------- pairwise via MFMA ----------------
// grid: qt(7) * t(2) * rg(32) * wh(2) = 896 blocks, 256 threads.
// Block: 16 q x 4 rows x 64 cols. K-map: k=(lane>>4)*8+j <-> (pixel quadrant, e)
// identical for A and B fragments, so any HW k-permutation cancels.
__launch_bounds__(256, 2)
__global__ void k_pair(const float* __restrict__ om,
                       const uint32_t* __restrict__ packed,
                       const int* __restrict__ cnt,
                       float* __restrict__ out) {
    int bid = blockIdx.x;
    int wh = bid & 1;
    int rg = (bid >> 1) & 31;
    int t  = (bid >> 6) & 1;
    int qt = bid >> 7;
    int qbase = qt * 16;
    int rowbase = rg * 4;
    int cbase = wh * 64;

    __shared__ uint32_t tile[16 * 580];   // [q][row(8)][col(72)], q-stride 580 (bank spread)
    __shared__ float red[4][16][17];

    int tid = threadIdx.x;

    // stage (x, sp(-x)) as half2: rows rowbase-2..+5, cols cbase-2..+65
    #pragma unroll
    for (int i = 0; i < 32; ++i) {       // main strip: cols 0..63
        int idx = i * 256 + tid;
        int col = idx & 63;
        int row = (idx >> 6) & 7;
        int q   = idx >> 9;
        int gq = qbase + q;
        int grow = rowbase - 2 + row;
        int gcol = cbase - 2 + col;
        float x = 0.0f;
        if (gq < Q_ && (unsigned)grow < (unsigned)H_ && (unsigned)gcol < (unsigned)W_)
            x = om[(((size_t)gq * T_ + t) * H_ + grow) * W_ + gcol];
        __half2 h2 = __floats2half2_rn(x, sp_(-x));
        tile[q * 580 + row * 72 + col] = *(uint32_t*)&h2;
    }
    #pragma unroll
    for (int i = 0; i < 2; ++i) {        // tail strip: cols 64..67
        int idx = i * 256 + tid;
        int col = 64 + (idx & 3);
        int row = (idx >> 2) & 7;
        int q   = idx >> 5;
        int gq = qbase + q;
        int grow = rowbase - 2 + row;
        int gcol = cbase - 2 + col;
        float x = 0.0f;
        if (gq < Q_ && (unsigned)grow < (unsigned)H_ && (unsigned)gcol < (unsigned)W_)
            x = om[(((size_t)gq * T_ + t) * H_ + grow) * W_ + gcol];
        __half2 h2 = __floats2half2_rn(x, sp_(-x));
        tile[q * 580 + row * 72 + col] = *(uint32_t*)&h2;
    }
    __syncthreads();

    int l = tid & 63;
    int w = tid >> 6;            // wave = local row 0..3
    int mn = l & 15;             // A-row (q-rel) for A-frag, B-col (g) for B-frag
    int pq = l >> 4;             // pixel within k-step quadrant
    int growS = rowbase + w;     // global row of this wave's pixels

    const uint32_t* tq = &tile[mn * 580 + (w + 2) * 72];

    const int dy[8] = {-2,-2,-2, 0,0, 2,2,2};
    const int dx[8] = {-2, 0, 2,-2,2,-2,0,2};

    floatx4 acc0 = {0.f,0.f,0.f,0.f}, acc1 = {0.f,0.f,0.f,0.f};

    #pragma unroll
    for (int grp = 0; grp < 16; ++grp) {
        int cloc = grp * 4 + pq;
        int sc = cloc + 2;
        int gcol = cbase + cloc;
        // B byte: g = mn, pixel (growS, gcol)
        int pix = (growS << 7) + gcol;
        uint32_t bw = packed[((size_t)t * HW_ + pix) * 4 + (mn >> 2)];
        uint32_t byte = (bw >> ((mn & 3) * 8)) & 255u;

        uint32_t selfw = tq[sc];
        __half2 selfh = *(__half2*)&selfw;
        float xs   = __half2float(__low2half(selfh));
        float spms = __half2float(__high2half(selfh));

        half8 af, bf;
        #pragma unroll
        for (int e = 0; e < 8; ++e) {
            uint32_t nw = tq[dy[e] * 72 + sc + dx[e]];
            __half2 nh = *(__half2*)&nw;
            float xn  = __half2float(__low2half(nh));
            float spn = __half2float(__high2half(nh));
            float s = spms + spn - sp_(-(xs + xn));
            bool ok = ((unsigned)(growS + dy[e]) < (unsigned)H_) &&
                      ((unsigned)(gcol + dx[e]) < (unsigned)W_);
            s = ok ? s : 0.0f;
            af[e] = (_Float16)s;
            bf[e] = (_Float16)(float)((byte >> e) & 1u);
        }
        if (grp & 1) acc1 = __builtin_amdgcn_mfma_f32_16x16x32_f16(af, bf, acc1, 0, 0, 0);
        else         acc0 = __builtin_amdgcn_mfma_f32_16x16x32_f16(af, bf, acc0, 0, 0, 0);
    }

    // C/D layout: col = lane&15 (g), row = (lane>>4)*4 + j (q-rel)
    #pragma unroll
    for (int j = 0; j < 4; ++j)
        red[w][pq * 4 + j][mn] = acc0[j] + acc1[j];
    __syncthreads();

    {
        int row = tid >> 4, g = tid & 15;
        float v = red[0][row][g] + red[1][row][g] + red[2][row][g] + red[3][row][g];
        int gq = qbase + row;
        if (gq < Q_) {
            int den = max(1, cnt[t * G_ + g]);
            atomicAdd(&out[gq * G_ + g], v * (0.5f / (float)den));
        }
    }
}

extern "C" void kernel_launch(void* const* d_in, const int* in_sizes, int n_in,
                              void* d_out, int out_size, void* d_ws, size_t ws_size,
                              hipStream_t stream) {
    const float* pred_logits = (const float*)d_in[0];
    const float* out_mask    = (const float*)d_in[1];
    const float* sims        = (const float*)d_in[2];
    const int*   tgt_ids     = (const int*)d_in[3];
    const int*   tgt_box     = (const int*)d_in[4];
    float* out = (float*)d_out;

    // workspace layout (4B units):
    // [srcMW 25600][tgtMWi 4096][srcMHu 25600][tgtMHi 4096][cnt 32][packed 131072]
    float*    srcMW  = (float*)d_ws;
    int*      tgtMWi = (int*)(srcMW + Q_ * T_ * 128);
    unsigned* srcMHu = (unsigned*)(tgtMWi + G_ * T_ * 128);
    int*      tgtMHi = (int*)(srcMHu + Q_ * T_ * 128);
    int*      cnt    = tgtMHi + G_ * T_ * 128;
    uint32_t* packed = (uint32_t*)(cnt + G_ * T_);

    // zero the atomic-reduce targets (srcMHu | tgtMHi | cnt are contiguous)
    int nzero = Q_ * T_ * 128 + G_ * T_ * 128 + G_ * T_;
    k_zero<<<(nzero + 255) / 256, 256, 0, stream>>>(srcMHu, nzero);

    k_srcmax<<<Q_ * T_ * 4, 256, 0, stream>>>(out_mask, srcMW, srcMHu);
    k_tgtmax<<<G_ * T_ * 8, 256, 0, stream>>>(tgt_box, tgtMWi, tgtMHi);
    k_pack<<<(T_ * HW_ / 256) * 4, 256, 0, stream>>>(sims, tgt_box, packed, cnt);
    k_dice<<<Q_ * G_, 64, 0, stream>>>(pred_logits, tgt_ids, srcMW, srcMHu, tgtMWi, tgtMHi, out);
    k_pair<<<7 * T_ * 32 * 2, 256, 0, stream>>>(out_mask, packed, cnt, out);
}

// Round 6
// 122.203 us; speedup vs baseline: 2.1654x; 1.1654x over previous
//
#include <hip/hip_runtime.h>
#include <hip/hip_fp16.h>
#include <cstdint>

#define Q_ 100
#define G_ 16
#define T_ 2
#define H_ 128
#define W_ 128
#define HW_ (H_*W_)
#define C_ 81
#define RS_ 69            // tile row stride (u32 words), == 5 mod 32
#define QS_ 553           // tile q stride = 8*69+1, == 9 mod 32

typedef _Float16 half8 __attribute__((ext_vector_type(8)));
typedef float floatx4 __attribute__((ext_vector_type(4)));

__device__ __forceinline__ float sig_(float x) { return 1.0f / (1.0f + __expf(-x)); }

// ---------------- src projection maxes: (qt, 32-row group), no atomics ----------------
__launch_bounds__(256)
__global__ void k_srcmax(const float* __restrict__ om,
                         float* __restrict__ srcMW,     // (QT,128) row-max (max over W)
                         float* __restrict__ srcMHp) {  // (QT,4,128) col-max partials
    int qt = blockIdx.x >> 2;
    int rg = blockIdx.x & 3;
    const float* base = om + (size_t)qt * HW_ + rg * 32 * W_;
    int tid = threadIdx.x;

    // row max: r = tid>>3 (32 rows), seg = tid&7 (16 floats each)
    {
        int r = tid >> 3, seg = tid & 7;
        const float4* rp = (const float4*)(base + r * W_ + seg * 16);
        float m = -1e30f;
        #pragma unroll
        for (int i = 0; i < 4; ++i) {
            float4 v = rp[i];
            m = fmaxf(m, fmaxf(fmaxf(v.x, v.y), fmaxf(v.z, v.w)));
        }
        m = fmaxf(m, __shfl_xor(m, 1, 64));
        m = fmaxf(m, __shfl_xor(m, 2, 64));
        m = fmaxf(m, __shfl_xor(m, 4, 64));
        if (seg == 0) srcMW[qt * 128 + rg * 32 + r] = m;
    }
    // col max over this block's 32 rows: c = tid&127, rh = tid>>7 (16 rows each)
    __shared__ float cred[128];
    {
        int c = tid & 127, rh = tid >> 7;
        const float* cp = base + rh * 16 * W_ + c;
        float m = -1e30f;
        #pragma unroll
        for (int i = 0; i < 16; ++i) m = fmaxf(m, cp[i * W_]);
        if (rh == 1) cred[c] = m;
        __syncthreads();
        if (rh == 0) srcMHp[(qt * 4 + rg) * 128 + c] = fmaxf(m, cred[c]);
    }
}

// ---------------- tgt projection maxes: (gt, 16-row group), no atomics ----------------
__launch_bounds__(256)
__global__ void k_tgtmax(const int* __restrict__ box,
                         int* __restrict__ tgtMWi,    // (GT,128) row-max
                         int* __restrict__ tgtMHp) {  // (GT,8,128) col-max partials
    int gt = blockIdx.x >> 3;
    int rg = blockIdx.x & 7;
    const int* base = box + (size_t)gt * HW_ + rg * 16 * W_;
    int tid = threadIdx.x;
    {
        int r = tid >> 4, seg = tid & 15;
        const int4* rp = (const int4*)(base + r * W_ + seg * 8);
        int4 a = rp[0], b = rp[1];
        int m = max(max(max(a.x, a.y), max(a.z, a.w)),
                    max(max(b.x, b.y), max(b.z, b.w)));
        m = max(m, __shfl_xor(m, 1, 64));
        m = max(m, __shfl_xor(m, 2, 64));
        m = max(m, __shfl_xor(m, 4, 64));
        m = max(m, __shfl_xor(m, 8, 64));
        if (seg == 0) tgtMWi[gt * 128 + rg * 16 + r] = m;
    }
    __shared__ int credi[128];
    {
        int c = tid & 127, rh = tid >> 7;
        const int* cp = base + rh * 8 * W_ + c;
        int m = 0;
        #pragma unroll
        for (int i = 0; i < 8; ++i) m = max(m, cp[i * W_]);
        if (rh == 1) credi[c] = m;
        __syncthreads();
        if (rh == 0) tgtMHp[(gt * 8 + rg) * 128 + c] = max(m, credi[c]);
    }
}

// ---------------- pack tgt bits, gg-major; 2 px/thread; partial counts ----------------
__launch_bounds__(256)
__global__ void k_pack(const float* __restrict__ sims,
                       const int* __restrict__ box,
                       uint32_t* __restrict__ packed,   // [4][T*HW]
                       int* __restrict__ cnt_part) {    // [64 pxblk][16 g]
    int bid = blockIdx.x;          // pxblk*4 + gg
    int gg = bid & 3;
    int pxblk = bid >> 2;
    int tid = threadIdx.x;
    int p0 = pxblk * 512 + tid * 2;        // 512 px per block, 2 per thread
    int t = p0 >> 14;
    int pp = p0 & (HW_ - 1);

    uint32_t w0 = 0, w1 = 0;
    int pc[4];
    #pragma unroll
    for (int b = 0; b < 4; ++b) {
        int g = gg * 4 + b;
        const float* sbase = sims + ((size_t)(g * T_ + t) * 8) * HW_ + pp;
        int2 bx = *(const int2*)(box + (size_t)(g * T_ + t) * HW_ + pp);
        uint32_t by0 = 0, by1 = 0;
        #pragma unroll
        for (int e = 0; e < 8; ++e) {
            float2 sv = *(const float2*)(sbase + (size_t)e * HW_);
            by0 |= (sv.x >= 0.3f ? 1u : 0u) << e;
            by1 |= (sv.y >= 0.3f ? 1u : 0u) << e;
        }
        by0 = bx.x ? by0 : 0u;
        by1 = bx.y ? by1 : 0u;
        w0 |= by0 << (b * 8);
        w1 |= by1 << (b * 8);
        pc[b] = __popc(by0) + __popc(by1);
    }
    *(uint2*)&packed[(size_t)gg * (T_ * HW_) + p0] = make_uint2(w0, w1);

    __shared__ int redI[4][4];
    int wid = tid >> 6, lane = tid & 63;
    #pragma unroll
    for (int b = 0; b < 4; ++b) {
        int s = pc[b];
        #pragma unroll
        for (int o = 32; o > 0; o >>= 1) s += __shfl_down(s, o, 64);
        if (lane == 0) redI[wid][b] = s;
    }
    __syncthreads();
    if (tid < 4)
        cnt_part[pxblk * 16 + gg * 4 + tid] =
            redI[0][tid] + redI[1][tid] + redI[2][tid] + redI[3][tid];
}

// ---------------- dice + class cost; one wave per (q,g); q==0 blocks reduce cnt ----------------
__global__ void k_dice(const float* __restrict__ logits, const int* __restrict__ ids,
                       const float* __restrict__ srcMW, const float* __restrict__ srcMHp,
                       const int* __restrict__ tgtMWi, const int* __restrict__ tgtMHp,
                       const int* __restrict__ cnt_part,
                       int* __restrict__ cntF,
                       float* __restrict__ out) {
    int q = blockIdx.x >> 4;
    int g = blockIdx.x & 15;
    int l = threadIdx.x;  // 64

    if (q == 0) {   // reduce pair-denominator partials (16 blocks do this)
        int tt = l >> 5, pb = l & 31;
        int v = cnt_part[(tt * 32 + pb) * 16 + g];
        #pragma unroll
        for (int o = 1; o <= 16; o <<= 1) v += __shfl_xor(v, o, 64);
        if (pb == 0) cntF[tt * G_ + g] = v;
    }

    // softmax over 81 logits
    float v0 = (l < C_) ? logits[q * C_ + l] : -1e30f;
    float v1 = (l + 64 < C_) ? logits[q * C_ + l + 64] : -1e30f;
    float mx = fmaxf(v0, v1);
    #pragma unroll
    for (int o = 32; o > 0; o >>= 1) mx = fmaxf(mx, __shfl_xor(mx, o, 64));
    float es = ((l < C_) ? __expf(v0 - mx) : 0.0f)
             + ((l + 64 < C_) ? __expf(v1 - mx) : 0.0f);
    #pragma unroll
    for (int o = 32; o > 0; o >>= 1) es += __shfl_xor(es, o, 64);

    float d3 = 0, t3 = 0, s3 = 0, d2 = 0, t2 = 0, s2 = 0;
    #pragma unroll
    for (int i = 0; i < 4; ++i) {
        int c = i * 64 + l;          // (t,pos) flattened over 256
        int tt = c >> 7, cc = c & 127;
        float sW = sig_(srcMW[(q * 2 + tt) * 128 + cc]);
        float mh = srcMHp[((q * 2 + tt) * 4 + 0) * 128 + cc];
        #pragma unroll
        for (int r = 1; r < 4; ++r)
            mh = fmaxf(mh, srcMHp[((q * 2 + tt) * 4 + r) * 128 + cc]);
        float sH = sig_(mh);
        float tW = (float)tgtMWi[(g * 2 + tt) * 128 + cc];
        int th = tgtMHp[((g * 2 + tt) * 8 + 0) * 128 + cc];
        #pragma unroll
        for (int r = 1; r < 8; ++r)
            th = max(th, tgtMHp[((g * 2 + tt) * 8 + r) * 128 + cc]);
        float tH = (float)th;
        d3 += sW * tW; t3 += tW; s3 += sW;
        d2 += sH * tH; t2 += tH; s2 += sH;
    }
    #pragma unroll
    for (int o = 32; o > 0; o >>= 1) {
        d3 += __shfl_xor(d3, o, 64); t3 += __shfl_xor(t3, o, 64);
        s3 += __shfl_xor(s3, o, 64); d2 += __shfl_xor(d2, o, 64);
        t2 += __shfl_xor(t2, o, 64); s2 += __shfl_xor(s2, o, 64);
    }
    if (l == 0) {
        float p = __expf(logits[q * C_ + ids[g]] - mx) / es;
        float dice3 = 1.0f - (2.0f * d3 + 1.0f) / (s3 + t3 + 1.0f);
        float dice2 = 1.0f - (2.0f * d2 + 1.0f) / (s2 + t2 + 1.0f);
        out[q * G_ + g] = -p + dice3 + dice2;
    }
}

// ---------------- pairwise via MFMA ----------------
// Block: 16 q x 4 rows x 64 cols. Lane (mn = l&15, pq = l>>4); wave w = row.
// Pixel column for (grp, pq) = pq*16 + grp  -> bank = (9*mn + 16*pq) mod 32: exactly 2-way (free).
// s = Lp + Ln - log(1 + Ep*En), with (E,L) = (exp(-x), softplus(-x)) staged as half2.
__launch_bounds__(256, 4)
__global__ void k_pair(const float* __restrict__ om,
                       const uint32_t* __restrict__ packed,  // [4][T*HW]
                       const int* __restrict__ cntF,         // [T][G]
                       float* __restrict__ out) {
    int bid = blockIdx.x;
    int wh = bid & 1;
    int rg = (bid >> 1) & 31;
    int t  = (bid >> 6) & 1;
    int qt = bid >> 7;
    int qbase = qt * 16;
    int rowbase = rg * 4;
    int cbase = wh * 64;
    int tid = threadIdx.x;

    __shared__ uint32_t tile[16 * QS_];   // [q][row 8][col 69(68 used)] (E,L) half2

    // main strip: cols cbase..cbase+63 (aligned float4) -> tile cols 2..65
    #pragma unroll
    for (int i = 0; i < 8; ++i) {
        int idx = i * 256 + tid;
        int c4 = idx & 15;
        int row = (idx >> 4) & 7;
        int q = idx >> 7;
        int gq = qbase + q;
        int grow = rowbase - 2 + row;
        float4 x = make_float4(0.f, 0.f, 0.f, 0.f);
        if (gq < Q_ && (unsigned)grow < (unsigned)H_)
            x = *(const float4*)(om + (((size_t)gq * T_ + t) * H_ + grow) * W_ + cbase + c4 * 4);
        uint32_t* dst = &tile[q * QS_ + row * RS_ + 2 + c4 * 4];
        {
            float E = __expf(-x.x); __half2 h = __floats2half2_rn(E, __logf(1.f + E)); dst[0] = *(uint32_t*)&h;
        }{
            float E = __expf(-x.y); __half2 h = __floats2half2_rn(E, __logf(1.f + E)); dst[1] = *(uint32_t*)&h;
        }{
            float E = __expf(-x.z); __half2 h = __floats2half2_rn(E, __logf(1.f + E)); dst[2] = *(uint32_t*)&h;
        }{
            float E = __expf(-x.w); __half2 h = __floats2half2_rn(E, __logf(1.f + E)); dst[3] = *(uint32_t*)&h;
        }
    }
    // tail strip: tile cols {0,1,66,67} (gcol cbase-2,-1,+64,+65): 16q x 8r x 4 = 512
    // (round-5 bug was cc+62 -> wrote {64,65}, leaving {66,67} uninitialized -> NaN)
    #pragma unroll
    for (int i = 0; i < 2; ++i) {
        int idx = i * 256 + tid;
        int cc = idx & 3;
        int row = (idx >> 2) & 7;
        int q = idx >> 5;
        int col = (cc < 2) ? cc : cc + 64;
        int gcol = cbase - 2 + col;
        int gq = qbase + q;
        int grow = rowbase - 2 + row;
        float x = 0.f;
        if (gq < Q_ && (unsigned)grow < (unsigned)H_ && (unsigned)gcol < (unsigned)W_)
            x = om[(((size_t)gq * T_ + t) * H_ + grow) * W_ + gcol];
        float E = __expf(-x);
        __half2 h = __floats2half2_rn(E, __logf(1.f + E));
        tile[q * QS_ + row * RS_ + col] = *(uint32_t*)&h;
    }
    __syncthreads();

    int l = tid & 63;
    int w = tid >> 6;
    int mn = l & 15;
    int pq = l >> 4;
    int growS = rowbase + w;

    // preload this lane's 16 packed words (cols pq*16 .. pq*16+15), one gg stream
    const uint32_t* pbase = packed + (size_t)(mn >> 2) * (T_ * HW_) + t * HW_
                          + (growS << 7) + cbase + (pq << 4);
    uint4 pkA = *(const uint4*)(pbase + 0);
    uint4 pkB = *(const uint4*)(pbase + 4);
    uint4 pkC = *(const uint4*)(pbase + 8);
    uint4 pkD = *(const uint4*)(pbase + 12);
    uint32_t pkw[16] = {pkA.x, pkA.y, pkA.z, pkA.w, pkB.x, pkB.y, pkB.z, pkB.w,
                        pkC.x, pkC.y, pkC.z, pkC.w, pkD.x, pkD.y, pkD.z, pkD.w};

    const uint32_t* tq = &tile[mn * QS_ + (w + 2) * RS_ + 2 + (pq << 4)];

    bool rowU = (growS >= 2), rowD = (growS <= H_ - 3);
    int bsh = (mn & 3) * 8;

    const int dy[8] = {-2,-2,-2, 0,0, 2,2,2};
    const int dx[8] = {-2, 0, 2,-2,2,-2,0,2};

    floatx4 acc0 = {0.f,0.f,0.f,0.f}, acc1 = {0.f,0.f,0.f,0.f};

    #pragma unroll
    for (int grp = 0; grp < 16; ++grp) {
        int gcol = cbase + (pq << 4) + grp;
        bool colL = (gcol >= 2), colR = (gcol <= W_ - 3);
        bool m8[8] = {rowU && colL, rowU, rowU && colR,
                      colL, colR,
                      rowD && colL, rowD, rowD && colR};

        uint32_t selfw = tq[grp];
        __half2 sh = *(__half2*)&selfw;
        float Ep = __half2float(__low2half(sh));
        float Lp = __half2float(__high2half(sh));
        uint32_t byte = (pkw[grp] >> bsh) & 255u;

        half8 af, bf;
        #pragma unroll
        for (int e = 0; e < 8; ++e) {
            uint32_t nw = tq[grp + dy[e] * RS_ + dx[e]];
            __half2 nh = *(__half2*)&nw;
            float En = __half2float(__low2half(nh));
            float Ln = __half2float(__high2half(nh));
            float s = Lp + Ln - __logf(fmaf(Ep, En, 1.0f));
            s = m8[e] ? s : 0.0f;
            af[e] = (_Float16)s;
            bf[e] = (_Float16)(float)((byte >> e) & 1u);
        }
        if (grp & 1) acc1 = __builtin_amdgcn_mfma_f32_16x16x32_f16(af, bf, acc1, 0, 0, 0);
        else         acc0 = __builtin_amdgcn_mfma_f32_16x16x32_f16(af, bf, acc0, 0, 0, 0);
    }

    __syncthreads();                 // done reading tile; reuse it as reduction buffer
    float* red = (float*)tile;       // [4][16][17]
    #pragma unroll
    for (int j = 0; j < 4; ++j)
        red[(w * 16 + pq * 4 + j) * 17 + mn] = acc0[j] + acc1[j];
    __syncthreads();
    {
        int row = tid >> 4, g = tid & 15;
        float v = red[(0 * 16 + row) * 17 + g] + red[(1 * 16 + row) * 17 + g]
                + red[(2 * 16 + row) * 17 + g] + red[(3 * 16 + row) * 17 + g];
        int gq = qbase + row;
        if (gq < Q_) {
            int den = max(1, cntF[t * G_ + g]);
            atomicAdd(&out[gq * G_ + g], v * (0.5f / (float)den));
        }
    }
}

extern "C" void kernel_launch(void* const* d_in, const int* in_sizes, int n_in,
                              void* d_out, int out_size, void* d_ws, size_t ws_size,
                              hipStream_t stream) {
    const float* pred_logits = (const float*)d_in[0];
    const float* out_mask    = (const float*)d_in[1];
    const float* sims        = (const float*)d_in[2];
    const int*   tgt_ids     = (const int*)d_in[3];
    const int*   tgt_box     = (const int*)d_in[4];
    float* out = (float*)d_out;

    // workspace layout (u32 units)
    float*    srcMW    = (float*)d_ws;                       // 25600
    float*    srcMHp   = srcMW + Q_ * T_ * 128;              // 102400
    int*      tgtMWi   = (int*)(srcMHp + Q_ * T_ * 4 * 128); // 4096
    int*      tgtMHp   = tgtMWi + G_ * T_ * 128;             // 32768
    int*      cnt_part = tgtMHp + G_ * T_ * 8 * 128;         // 1024
    int*      cntF     = cnt_part + 64 * 16;                 // 32
    uint32_t* packed   = (uint32_t*)(cntF + G_ * T_);        // 131072 (16B-aligned)

    k_srcmax<<<Q_ * T_ * 4, 256, 0, stream>>>(out_mask, srcMW, srcMHp);
    k_tgtmax<<<G_ * T_ * 8, 256, 0, stream>>>(tgt_box, tgtMWi, tgtMHp);
    k_pack<<<(T_ * HW_ / 512) * 4, 256, 0, stream>>>(sims, tgt_box, packed, cnt_part);
    k_dice<<<Q_ * G_, 64, 0, stream>>>(pred_logits, tgt_ids, srcMW, srcMHp,
                                       tgtMWi, tgtMHp, cnt_part, cntF, out);
    k_pair<<<7 * T_ * 32 * 2, 256, 0, stream>>>(out_mask, packed, cntF, out);
}

// Round 7
// 112.987 us; speedup vs baseline: 2.3420x; 1.0816x over previous
//
#include <hip/hip_runtime.h>
#include <hip/hip_fp16.h>
#include <cstdint>

#define Q_ 100
#define G_ 16
#define T_ 2
#define H_ 128
#define W_ 128
#define HW_ (H_*W_)
#define C_ 81
#define RS_ 69            // tile row stride (u32 words), == 5 mod 32
#define QS_ 553           // tile q stride = 8*69+1, == 9 mod 32

typedef _Float16 half8 __attribute__((ext_vector_type(8)));
typedef float floatx4 __attribute__((ext_vector_type(4)));

__device__ __forceinline__ float sig_(float x) { return 1.0f / (1.0f + __expf(-x)); }

// ---------------- fused prep: srcmax (0..799) | tgtmax (800..1055) | pack (1056..1311) ----------------
__launch_bounds__(256)
__global__ void k_prep(const float* __restrict__ om,
                       const int* __restrict__ box,
                       const float* __restrict__ sims,
                       float* __restrict__ srcMW,     // (QT,128) row-max
                       float* __restrict__ srcMHp,    // (QT,4,128) col-max partials
                       int* __restrict__ tgtMWi,      // (GT,128) row-max
                       int* __restrict__ tgtMHp,      // (GT,8,128) col-max partials
                       uint32_t* __restrict__ packed, // [4][T*HW]
                       int* __restrict__ cnt_part) {  // [64 pxblk][16 g]
    __shared__ float credF[128];
    __shared__ int redI[4][4];
    int bid = blockIdx.x;
    int tid = threadIdx.x;

    if (bid < 800) {
        // ---- srcmax: (qt, 32-row group) ----
        int qt = bid >> 2;
        int rg = bid & 3;
        const float* base = om + (size_t)qt * HW_ + rg * 32 * W_;
        {
            int r = tid >> 3, seg = tid & 7;
            const float4* rp = (const float4*)(base + r * W_ + seg * 16);
            float m = -1e30f;
            #pragma unroll
            for (int i = 0; i < 4; ++i) {
                float4 v = rp[i];
                m = fmaxf(m, fmaxf(fmaxf(v.x, v.y), fmaxf(v.z, v.w)));
            }
            m = fmaxf(m, __shfl_xor(m, 1, 64));
            m = fmaxf(m, __shfl_xor(m, 2, 64));
            m = fmaxf(m, __shfl_xor(m, 4, 64));
            if (seg == 0) srcMW[qt * 128 + rg * 32 + r] = m;
        }
        {
            int c = tid & 127, rh = tid >> 7;
            const float* cp = base + rh * 16 * W_ + c;
            float m = -1e30f;
            #pragma unroll
            for (int i = 0; i < 16; ++i) m = fmaxf(m, cp[i * W_]);
            if (rh == 1) credF[c] = m;
            __syncthreads();
            if (rh == 0) srcMHp[(qt * 4 + rg) * 128 + c] = fmaxf(m, credF[c]);
        }
    } else if (bid < 1056) {
        // ---- tgtmax: (gt, 16-row group) ----
        int b2 = bid - 800;
        int gt = b2 >> 3;
        int rg = b2 & 7;
        const int* base = box + (size_t)gt * HW_ + rg * 16 * W_;
        {
            int r = tid >> 4, seg = tid & 15;
            const int4* rp = (const int4*)(base + r * W_ + seg * 8);
            int4 a = rp[0], b = rp[1];
            int m = max(max(max(a.x, a.y), max(a.z, a.w)),
                        max(max(b.x, b.y), max(b.z, b.w)));
            m = max(m, __shfl_xor(m, 1, 64));
            m = max(m, __shfl_xor(m, 2, 64));
            m = max(m, __shfl_xor(m, 4, 64));
            m = max(m, __shfl_xor(m, 8, 64));
            if (seg == 0) tgtMWi[gt * 128 + rg * 16 + r] = m;
        }
        {
            int* credi = (int*)credF;
            int c = tid & 127, rh = tid >> 7;
            const int* cp = base + rh * 8 * W_ + c;
            int m = 0;
            #pragma unroll
            for (int i = 0; i < 8; ++i) m = max(m, cp[i * W_]);
            if (rh == 1) credi[c] = m;
            __syncthreads();
            if (rh == 0) tgtMHp[(gt * 8 + rg) * 128 + c] = max(m, credi[c]);
        }
    } else {
        // ---- pack: 512 px per block, 2 per thread ----
        int b3 = bid - 1056;
        int gg = b3 & 3;
        int pxblk = b3 >> 2;
        int p0 = pxblk * 512 + tid * 2;
        int t = p0 >> 14;
        int pp = p0 & (HW_ - 1);

        uint32_t w0 = 0, w1 = 0;
        int pc[4];
        #pragma unroll
        for (int b = 0; b < 4; ++b) {
            int g = gg * 4 + b;
            const float* sbase = sims + ((size_t)(g * T_ + t) * 8) * HW_ + pp;
            int2 bx = *(const int2*)(box + (size_t)(g * T_ + t) * HW_ + pp);
            uint32_t by0 = 0, by1 = 0;
            #pragma unroll
            for (int e = 0; e < 8; ++e) {
                float2 sv = *(const float2*)(sbase + (size_t)e * HW_);
                by0 |= (sv.x >= 0.3f ? 1u : 0u) << e;
                by1 |= (sv.y >= 0.3f ? 1u : 0u) << e;
            }
            by0 = bx.x ? by0 : 0u;
            by1 = bx.y ? by1 : 0u;
            w0 |= by0 << (b * 8);
            w1 |= by1 << (b * 8);
            pc[b] = __popc(by0) + __popc(by1);
        }
        *(uint2*)&packed[(size_t)gg * (T_ * HW_) + p0] = make_uint2(w0, w1);

        int wid = tid >> 6, lane = tid & 63;
        #pragma unroll
        for (int b = 0; b < 4; ++b) {
            int s = pc[b];
            #pragma unroll
            for (int o = 32; o > 0; o >>= 1) s += __shfl_down(s, o, 64);
            if (lane == 0) redI[wid][b] = s;
        }
        __syncthreads();
        if (tid < 4)
            cnt_part[pxblk * 16 + gg * 4 + tid] =
                redI[0][tid] + redI[1][tid] + redI[2][tid] + redI[3][tid];
    }
}

// ---------------- dice + class cost; one wave per (q,g); q==0 blocks reduce cnt ----------------
__global__ void k_dice(const float* __restrict__ logits, const int* __restrict__ ids,
                       const float* __restrict__ srcMW, const float* __restrict__ srcMHp,
                       const int* __restrict__ tgtMWi, const int* __restrict__ tgtMHp,
                       const int* __restrict__ cnt_part,
                       int* __restrict__ cntF,
                       float* __restrict__ out) {
    int q = blockIdx.x >> 4;
    int g = blockIdx.x & 15;
    int l = threadIdx.x;  // 64

    if (q == 0) {   // reduce pair-denominator partials (16 blocks do this)
        int tt = l >> 5, pb = l & 31;
        int v = cnt_part[(tt * 32 + pb) * 16 + g];
        #pragma unroll
        for (int o = 1; o <= 16; o <<= 1) v += __shfl_xor(v, o, 64);
        if (pb == 0) cntF[tt * G_ + g] = v;
    }

    // softmax over 81 logits
    float v0 = (l < C_) ? logits[q * C_ + l] : -1e30f;
    float v1 = (l + 64 < C_) ? logits[q * C_ + l + 64] : -1e30f;
    float mx = fmaxf(v0, v1);
    #pragma unroll
    for (int o = 32; o > 0; o >>= 1) mx = fmaxf(mx, __shfl_xor(mx, o, 64));
    float es = ((l < C_) ? __expf(v0 - mx) : 0.0f)
             + ((l + 64 < C_) ? __expf(v1 - mx) : 0.0f);
    #pragma unroll
    for (int o = 32; o > 0; o >>= 1) es += __shfl_xor(es, o, 64);

    float d3 = 0, t3 = 0, s3 = 0, d2 = 0, t2 = 0, s2 = 0;
    #pragma unroll
    for (int i = 0; i < 4; ++i) {
        int c = i * 64 + l;          // (t,pos) flattened over 256
        int tt = c >> 7, cc = c & 127;
        float sW = sig_(srcMW[(q * 2 + tt) * 128 + cc]);
        float mh = srcMHp[((q * 2 + tt) * 4 + 0) * 128 + cc];
        #pragma unroll
        for (int r = 1; r < 4; ++r)
            mh = fmaxf(mh, srcMHp[((q * 2 + tt) * 4 + r) * 128 + cc]);
        float sH = sig_(mh);
        float tW = (float)tgtMWi[(g * 2 + tt) * 128 + cc];
        int th = tgtMHp[((g * 2 + tt) * 8 + 0) * 128 + cc];
        #pragma unroll
        for (int r = 1; r < 8; ++r)
            th = max(th, tgtMHp[((g * 2 + tt) * 8 + r) * 128 + cc]);
        float tH = (float)th;
        d3 += sW * tW; t3 += tW; s3 += sW;
        d2 += sH * tH; t2 += tH; s2 += sH;
    }
    #pragma unroll
    for (int o = 32; o > 0; o >>= 1) {
        d3 += __shfl_xor(d3, o, 64); t3 += __shfl_xor(t3, o, 64);
        s3 += __shfl_xor(s3, o, 64); d2 += __shfl_xor(d2, o, 64);
        t2 += __shfl_xor(t2, o, 64); s2 += __shfl_xor(s2, o, 64);
    }
    if (l == 0) {
        float p = __expf(logits[q * C_ + ids[g]] - mx) / es;
        float dice3 = 1.0f - (2.0f * d3 + 1.0f) / (s3 + t3 + 1.0f);
        float dice2 = 1.0f - (2.0f * d2 + 1.0f) / (s2 + t2 + 1.0f);
        out[q * G_ + g] = -p + dice3 + dice2;
    }
}

// ---------------- pairwise via MFMA ----------------
// Block: 16 q x 4 rows x 64 cols. Lane (mn = l&15, pq = l>>4); wave w = row.
// Pixel column for (grp, pq) = pq*16 + grp  -> bank = (9*mn + 16*pq) mod 32: exactly 2-way (free).
// s = Lp + Ln - log(1 + Ep*En), with (E,L) = (exp(-x), softplus(-x)) staged as half2.
__launch_bounds__(256, 4)
__global__ void k_pair(const float* __restrict__ om,
                       const uint32_t* __restrict__ packed,  // [4][T*HW]
                       const int* __restrict__ cntF,         // [T][G]
                       float* __restrict__ out) {
    int bid = blockIdx.x;
    int wh = bid & 1;
    int rg = (bid >> 1) & 31;
    int t  = (bid >> 6) & 1;
    int qt = bid >> 7;
    int qbase = qt * 16;
    int rowbase = rg * 4;
    int cbase = wh * 64;
    int tid = threadIdx.x;

    __shared__ uint32_t tile[16 * QS_];   // [q][row 8][col 69(68 used)] (E,L) half2

    // main strip: cols cbase..cbase+63 (aligned float4) -> tile cols 2..65
    #pragma unroll
    for (int i = 0; i < 8; ++i) {
        int idx = i * 256 + tid;
        int c4 = idx & 15;
        int row = (idx >> 4) & 7;
        int q = idx >> 7;
        int gq = qbase + q;
        int grow = rowbase - 2 + row;
        float4 x = make_float4(0.f, 0.f, 0.f, 0.f);
        if (gq < Q_ && (unsigned)grow < (unsigned)H_)
            x = *(const float4*)(om + (((size_t)gq * T_ + t) * H_ + grow) * W_ + cbase + c4 * 4);
        uint32_t* dst = &tile[q * QS_ + row * RS_ + 2 + c4 * 4];
        {
            float E = __expf(-x.x); __half2 h = __floats2half2_rn(E, __logf(1.f + E)); dst[0] = *(uint32_t*)&h;
        }{
            float E = __expf(-x.y); __half2 h = __floats2half2_rn(E, __logf(1.f + E)); dst[1] = *(uint32_t*)&h;
        }{
            float E = __expf(-x.z); __half2 h = __floats2half2_rn(E, __logf(1.f + E)); dst[2] = *(uint32_t*)&h;
        }{
            float E = __expf(-x.w); __half2 h = __floats2half2_rn(E, __logf(1.f + E)); dst[3] = *(uint32_t*)&h;
        }
    }
    // tail strip: tile cols {0,1,66,67} (gcol cbase-2,-1,+64,+65)
    #pragma unroll
    for (int i = 0; i < 2; ++i) {
        int idx = i * 256 + tid;
        int cc = idx & 3;
        int row = (idx >> 2) & 7;
        int q = idx >> 5;
        int col = (cc < 2) ? cc : cc + 64;
        int gcol = cbase - 2 + col;
        int gq = qbase + q;
        int grow = rowbase - 2 + row;
        float x = 0.f;
        if (gq < Q_ && (unsigned)grow < (unsigned)H_ && (unsigned)gcol < (unsigned)W_)
            x = om[(((size_t)gq * T_ + t) * H_ + grow) * W_ + gcol];
        float E = __expf(-x);
        __half2 h = __floats2half2_rn(E, __logf(1.f + E));
        tile[q * QS_ + row * RS_ + col] = *(uint32_t*)&h;
    }
    __syncthreads();

    int l = tid & 63;
    int w = tid >> 6;
    int mn = l & 15;
    int pq = l >> 4;
    int growS = rowbase + w;

    // preload this lane's 16 packed words (cols pq*16 .. pq*16+15), one gg stream
    const uint32_t* pbase = packed + (size_t)(mn >> 2) * (T_ * HW_) + t * HW_
                          + (growS << 7) + cbase + (pq << 4);
    uint4 pkA = *(const uint4*)(pbase + 0);
    uint4 pkB = *(const uint4*)(pbase + 4);
    uint4 pkC = *(const uint4*)(pbase + 8);
    uint4 pkD = *(const uint4*)(pbase + 12);
    uint32_t pkw[16] = {pkA.x, pkA.y, pkA.z, pkA.w, pkB.x, pkB.y, pkB.z, pkB.w,
                        pkC.x, pkC.y, pkC.z, pkC.w, pkD.x, pkD.y, pkD.z, pkD.w};

    const uint32_t* tq = &tile[mn * QS_ + (w + 2) * RS_ + 2 + (pq << 4)];

    bool rowU = (growS >= 2), rowD = (growS <= H_ - 3);
    int bsh = (mn & 3) * 8;

    const int dy[8] = {-2,-2,-2, 0,0, 2,2,2};
    const int dx[8] = {-2, 0, 2,-2,2,-2,0,2};

    floatx4 acc0 = {0.f,0.f,0.f,0.f}, acc1 = {0.f,0.f,0.f,0.f};

    #pragma unroll
    for (int grp = 0; grp < 16; ++grp) {
        int gcol = cbase + (pq << 4) + grp;
        bool colL = (gcol >= 2), colR = (gcol <= W_ - 3);
        bool m8[8] = {rowU && colL, rowU, rowU && colR,
                      colL, colR,
                      rowD && colL, rowD, rowD && colR};

        uint32_t selfw = tq[grp];
        __half2 sh = *(__half2*)&selfw;
        float Ep = __half2float(__low2half(sh));
        float Lp = __half2float(__high2half(sh));
        uint32_t byte = (pkw[grp] >> bsh) & 255u;

        half8 af;
        #pragma unroll
        for (int e = 0; e < 8; ++e) {
            uint32_t nw = tq[grp + dy[e] * RS_ + dx[e]];
            __half2 nh = *(__half2*)&nw;
            float En = __half2float(__low2half(nh));
            float Ln = __half2float(__high2half(nh));
            float s = Lp + Ln - __logf(fmaf(Ep, En, 1.0f));
            s = m8[e] ? s : 0.0f;
            af[e] = (_Float16)s;
        }
        // B fragment: bit -> f16 1.0 via spread-multiply (0x10001 * 0x3C00 = 0x3C003C00)
        union { half8 h; uint32_t w4[4]; } bfu;
        uint32_t xb = byte | (byte << 15);
        bfu.w4[0] = ((xb >> 0) & 0x10001u) * 0x3C00u;
        bfu.w4[1] = ((xb >> 2) & 0x10001u) * 0x3C00u;
        bfu.w4[2] = ((xb >> 4) & 0x10001u) * 0x3C00u;
        bfu.w4[3] = ((xb >> 6) & 0x10001u) * 0x3C00u;

        if (grp & 1) acc1 = __builtin_amdgcn_mfma_f32_16x16x32_f16(af, bfu.h, acc1, 0, 0, 0);
        else         acc0 = __builtin_amdgcn_mfma_f32_16x16x32_f16(af, bfu.h, acc0, 0, 0, 0);
    }

    __syncthreads();                 // done reading tile; reuse it as reduction buffer
    float* red = (float*)tile;       // [4][16][17]
    #pragma unroll
    for (int j = 0; j < 4; ++j)
        red[(w * 16 + pq * 4 + j) * 17 + mn] = acc0[j] + acc1[j];
    __syncthreads();
    {
        int row = tid >> 4, g = tid & 15;
        float v = red[(0 * 16 + row) * 17 + g] + red[(1 * 16 + row) * 17 + g]
                + red[(2 * 16 + row) * 17 + g] + red[(3 * 16 + row) * 17 + g];
        int gq = qbase + row;
        if (gq < Q_) {
            int den = max(1, cntF[t * G_ + g]);
            atomicAdd(&out[gq * G_ + g], v * (0.5f / (float)den));
        }
    }
}

extern "C" void kernel_launch(void* const* d_in, const int* in_sizes, int n_in,
                              void* d_out, int out_size, void* d_ws, size_t ws_size,
                              hipStream_t stream) {
    const float* pred_logits = (const float*)d_in[0];
    const float* out_mask    = (const float*)d_in[1];
    const float* sims        = (const float*)d_in[2];
    const int*   tgt_ids     = (const int*)d_in[3];
    const int*   tgt_box     = (const int*)d_in[4];
    float* out = (float*)d_out;

    // workspace layout (u32 units)
    float*    srcMW    = (float*)d_ws;                       // 25600
    float*    srcMHp   = srcMW + Q_ * T_ * 128;              // 102400
    int*      tgtMWi   = (int*)(srcMHp + Q_ * T_ * 4 * 128); // 4096
    int*      tgtMHp   = tgtMWi + G_ * T_ * 128;             // 32768
    int*      cnt_part = tgtMHp + G_ * T_ * 8 * 128;         // 1024
    int*      cntF     = cnt_part + 64 * 16;                 // 32
    uint32_t* packed   = (uint32_t*)(cntF + G_ * T_);        // 131072 (16B-aligned)

    k_prep<<<1312, 256, 0, stream>>>(out_mask, tgt_box, sims,
                                     srcMW, srcMHp, tgtMWi, tgtMHp, packed, cnt_part);
    k_dice<<<Q_ * G_, 64, 0, stream>>>(pred_logits, tgt_ids, srcMW, srcMHp,
                                       tgtMWi, tgtMHp, cnt_part, cntF, out);
    k_pair<<<7 * T_ * 32 * 2, 256, 0, stream>>>(out_mask, packed, cntF, out);
}

// Round 8
// 110.203 us; speedup vs baseline: 2.4012x; 1.0253x over previous
//
#include <hip/hip_runtime.h>
#include <hip/hip_fp16.h>
#include <cstdint>

#define Q_ 100
#define G_ 16
#define T_ 2
#define H_ 128
#define W_ 128
#define HW_ (H_*W_)
#define C_ 81
#define RS_ 69            // tile row stride (u32 words), == 5 mod 32
#define QS_ 553           // tile q stride = 8*69+1, == 9 mod 32

typedef _Float16 half8 __attribute__((ext_vector_type(8)));
typedef float floatx4 __attribute__((ext_vector_type(4)));

__device__ __forceinline__ float sig_(float x) { return 1.0f / (1.0f + __expf(-x)); }

// ---------------- fused prep ----------------
// blocks 0..799  srcmax (qt, 32-row group)
// blocks 800..1055 tgtmax (gt, 16-row group)
// blocks 1056..1311 pack (512 px, one gg)
// block 1312 zero out[Q*G]
__launch_bounds__(256)
__global__ void k_prep(const float* __restrict__ om,
                       const int* __restrict__ box,
                       const float* __restrict__ sims,
                       float* __restrict__ srcMW,     // (QT,128) row-max
                       float* __restrict__ srcMHp,    // (QT,4,128) col-max partials
                       int* __restrict__ tgtMWi,      // (GT,128) row-max
                       int* __restrict__ tgtMHp,      // (GT,8,128) col-max partials
                       uint32_t* __restrict__ packed, // [4][T*HW]
                       int* __restrict__ cnt_part,    // [64 pxblk][16 g]
                       float* __restrict__ out) {     // zeroed by last block
    __shared__ float credF[128];
    __shared__ int redI[4][4];
    int bid = blockIdx.x;
    int tid = threadIdx.x;

    if (bid < 800) {
        // ---- srcmax ----
        int qt = bid >> 2;
        int rg = bid & 3;
        const float* base = om + (size_t)qt * HW_ + rg * 32 * W_;
        {
            int r = tid >> 3, seg = tid & 7;
            const float4* rp = (const float4*)(base + r * W_ + seg * 16);
            float m = -1e30f;
            #pragma unroll
            for (int i = 0; i < 4; ++i) {
                float4 v = rp[i];
                m = fmaxf(m, fmaxf(fmaxf(v.x, v.y), fmaxf(v.z, v.w)));
            }
            m = fmaxf(m, __shfl_xor(m, 1, 64));
            m = fmaxf(m, __shfl_xor(m, 2, 64));
            m = fmaxf(m, __shfl_xor(m, 4, 64));
            if (seg == 0) srcMW[qt * 128 + rg * 32 + r] = m;
        }
        {
            int c = tid & 127, rh = tid >> 7;
            const float* cp = base + rh * 16 * W_ + c;
            float m = -1e30f;
            #pragma unroll
            for (int i = 0; i < 16; ++i) m = fmaxf(m, cp[i * W_]);
            if (rh == 1) credF[c] = m;
            __syncthreads();
            if (rh == 0) srcMHp[(qt * 4 + rg) * 128 + c] = fmaxf(m, credF[c]);
        }
    } else if (bid < 1056) {
        // ---- tgtmax ----
        int b2 = bid - 800;
        int gt = b2 >> 3;
        int rg = b2 & 7;
        const int* base = box + (size_t)gt * HW_ + rg * 16 * W_;
        {
            int r = tid >> 4, seg = tid & 15;
            const int4* rp = (const int4*)(base + r * W_ + seg * 8);
            int4 a = rp[0], b = rp[1];
            int m = max(max(max(a.x, a.y), max(a.z, a.w)),
                        max(max(b.x, b.y), max(b.z, b.w)));
            m = max(m, __shfl_xor(m, 1, 64));
            m = max(m, __shfl_xor(m, 2, 64));
            m = max(m, __shfl_xor(m, 4, 64));
            m = max(m, __shfl_xor(m, 8, 64));
            if (seg == 0) tgtMWi[gt * 128 + rg * 16 + r] = m;
        }
        {
            int* credi = (int*)credF;
            int c = tid & 127, rh = tid >> 7;
            const int* cp = base + rh * 8 * W_ + c;
            int m = 0;
            #pragma unroll
            for (int i = 0; i < 8; ++i) m = max(m, cp[i * W_]);
            if (rh == 1) credi[c] = m;
            __syncthreads();
            if (rh == 0) tgtMHp[(gt * 8 + rg) * 128 + c] = max(m, credi[c]);
        }
    } else if (bid < 1312) {
        // ---- pack ----
        int b3 = bid - 1056;
        int gg = b3 & 3;
        int pxblk = b3 >> 2;
        int p0 = pxblk * 512 + tid * 2;
        int t = p0 >> 14;
        int pp = p0 & (HW_ - 1);

        uint32_t w0 = 0, w1 = 0;
        int pc[4];
        #pragma unroll
        for (int b = 0; b < 4; ++b) {
            int g = gg * 4 + b;
            const float* sbase = sims + ((size_t)(g * T_ + t) * 8) * HW_ + pp;
            int2 bx = *(const int2*)(box + (size_t)(g * T_ + t) * HW_ + pp);
            uint32_t by0 = 0, by1 = 0;
            #pragma unroll
            for (int e = 0; e < 8; ++e) {
                float2 sv = *(const float2*)(sbase + (size_t)e * HW_);
                by0 |= (sv.x >= 0.3f ? 1u : 0u) << e;
                by1 |= (sv.y >= 0.3f ? 1u : 0u) << e;
            }
            by0 = bx.x ? by0 : 0u;
            by1 = bx.y ? by1 : 0u;
            w0 |= by0 << (b * 8);
            w1 |= by1 << (b * 8);
            pc[b] = __popc(by0) + __popc(by1);
        }
        *(uint2*)&packed[(size_t)gg * (T_ * HW_) + p0] = make_uint2(w0, w1);

        int wid = tid >> 6, lane = tid & 63;
        #pragma unroll
        for (int b = 0; b < 4; ++b) {
            int s = pc[b];
            #pragma unroll
            for (int o = 32; o > 0; o >>= 1) s += __shfl_down(s, o, 64);
            if (lane == 0) redI[wid][b] = s;
        }
        __syncthreads();
        if (tid < 4)
            cnt_part[pxblk * 16 + gg * 4 + tid] =
                redI[0][tid] + redI[1][tid] + redI[2][tid] + redI[3][tid];
    } else {
        // ---- zero out (Q*G = 1600 floats) ----
        #pragma unroll
        for (int i = 0; i < 7; ++i) {
            int idx = i * 256 + tid;
            if (idx < Q_ * G_) out[idx] = 0.0f;
        }
    }
}

// ---------------- fused main: pair (blocks 0..895) + dice/class (blocks 896..1295) ----------------
// pair block: 16 q x 4 rows x 64 cols. Lane (mn = l&15, pq = l>>4); wave w = row.
// Pixel column (grp,pq) = pq*16+grp -> bank = (9*mn + 16*pq) mod 32: exactly 2-way (free).
// s = Lp + Ln - log(1 + Ep*En), (E,L) = (exp(-x), softplus(-x)) staged as half2.
// dice block: 4 waves, wave w handles (q,g) pair #(bid-896)*4+w; atomicAdd result.
__launch_bounds__(256, 4)
__global__ void k_main(const float* __restrict__ om,
                       const uint32_t* __restrict__ packed,  // [4][T*HW]
                       const int* __restrict__ cnt_part,     // [64][16]
                       const float* __restrict__ logits, const int* __restrict__ ids,
                       const float* __restrict__ srcMW, const float* __restrict__ srcMHp,
                       const int* __restrict__ tgtMWi, const int* __restrict__ tgtMHp,
                       float* __restrict__ out) {
    __shared__ uint32_t tile[16 * QS_];   // pair: staged (E,L); reused as f32 reduction buf
    __shared__ int cntS[16];
    int bid = blockIdx.x;
    int tid = threadIdx.x;

    if (bid < 896) {
        // ================= pair =================
        int wh = bid & 1;
        int rg = (bid >> 1) & 31;
        int t  = (bid >> 6) & 1;
        int qt = bid >> 7;
        int qbase = qt * 16;
        int rowbase = rg * 4;
        int cbase = wh * 64;

        // main strip: cols cbase..cbase+63 (aligned float4) -> tile cols 2..65
        #pragma unroll
        for (int i = 0; i < 8; ++i) {
            int idx = i * 256 + tid;
            int c4 = idx & 15;
            int row = (idx >> 4) & 7;
            int q = idx >> 7;
            int gq = qbase + q;
            int grow = rowbase - 2 + row;
            float4 x = make_float4(0.f, 0.f, 0.f, 0.f);
            if (gq < Q_ && (unsigned)grow < (unsigned)H_)
                x = *(const float4*)(om + (((size_t)gq * T_ + t) * H_ + grow) * W_ + cbase + c4 * 4);
            uint32_t* dst = &tile[q * QS_ + row * RS_ + 2 + c4 * 4];
            {
                float E = __expf(-x.x); __half2 h = __floats2half2_rn(E, __logf(1.f + E)); dst[0] = *(uint32_t*)&h;
            }{
                float E = __expf(-x.y); __half2 h = __floats2half2_rn(E, __logf(1.f + E)); dst[1] = *(uint32_t*)&h;
            }{
                float E = __expf(-x.z); __half2 h = __floats2half2_rn(E, __logf(1.f + E)); dst[2] = *(uint32_t*)&h;
            }{
                float E = __expf(-x.w); __half2 h = __floats2half2_rn(E, __logf(1.f + E)); dst[3] = *(uint32_t*)&h;
            }
        }
        // tail strip: tile cols {0,1,66,67} (gcol cbase-2,-1,+64,+65)
        #pragma unroll
        for (int i = 0; i < 2; ++i) {
            int idx = i * 256 + tid;
            int cc = idx & 3;
            int row = (idx >> 2) & 7;
            int q = idx >> 5;
            int col = (cc < 2) ? cc : cc + 64;
            int gcol = cbase - 2 + col;
            int gq = qbase + q;
            int grow = rowbase - 2 + row;
            float x = 0.f;
            if (gq < Q_ && (unsigned)grow < (unsigned)H_ && (unsigned)gcol < (unsigned)W_)
                x = om[(((size_t)gq * T_ + t) * H_ + grow) * W_ + gcol];
            float E = __expf(-x);
            __half2 h = __floats2half2_rn(E, __logf(1.f + E));
            tile[q * QS_ + row * RS_ + col] = *(uint32_t*)&h;
        }
        // per-block denominator self-reduction (overlaps staging latency)
        if (tid < 16) {
            int s = 0;
            #pragma unroll
            for (int i = 0; i < 32; ++i) s += cnt_part[(t * 32 + i) * 16 + tid];
            cntS[tid] = max(1, s);
        }
        __syncthreads();

        int l = tid & 63;
        int w = tid >> 6;
        int mn = l & 15;
        int pq = l >> 4;
        int growS = rowbase + w;

        // preload this lane's 16 packed words (cols pq*16..pq*16+15) of its gg plane
        const uint32_t* pbase = packed + (size_t)(mn >> 2) * (T_ * HW_) + t * HW_
                              + (growS << 7) + cbase + (pq << 4);
        uint4 pkA = *(const uint4*)(pbase + 0);
        uint4 pkB = *(const uint4*)(pbase + 4);
        uint4 pkC = *(const uint4*)(pbase + 8);
        uint4 pkD = *(const uint4*)(pbase + 12);
        uint32_t pkw[16] = {pkA.x, pkA.y, pkA.z, pkA.w, pkB.x, pkB.y, pkB.z, pkB.w,
                            pkC.x, pkC.y, pkC.z, pkC.w, pkD.x, pkD.y, pkD.z, pkD.w};

        const uint32_t* tq = &tile[mn * QS_ + (w + 2) * RS_ + 2 + (pq << 4)];

        bool rowU = (growS >= 2), rowD = (growS <= H_ - 3);
        int bsh = (mn & 3) * 8;

        const int dy[8] = {-2,-2,-2, 0,0, 2,2,2};
        const int dx[8] = {-2, 0, 2,-2,2,-2,0,2};

        floatx4 acc0 = {0.f,0.f,0.f,0.f}, acc1 = {0.f,0.f,0.f,0.f};

        #pragma unroll
        for (int grp = 0; grp < 16; ++grp) {
            int gcol = cbase + (pq << 4) + grp;
            bool colL = (gcol >= 2), colR = (gcol <= W_ - 3);
            bool m8[8] = {rowU && colL, rowU, rowU && colR,
                          colL, colR,
                          rowD && colL, rowD, rowD && colR};

            uint32_t selfw = tq[grp];
            __half2 sh = *(__half2*)&selfw;
            float Ep = __half2float(__low2half(sh));
            float Lp = __half2float(__high2half(sh));
            uint32_t byte = (pkw[grp] >> bsh) & 255u;

            half8 af;
            #pragma unroll
            for (int e = 0; e < 8; ++e) {
                uint32_t nw = tq[grp + dy[e] * RS_ + dx[e]];
                __half2 nh = *(__half2*)&nw;
                float En = __half2float(__low2half(nh));
                float Ln = __half2float(__high2half(nh));
                float s = Lp + Ln - __logf(fmaf(Ep, En, 1.0f));
                s = m8[e] ? s : 0.0f;
                af[e] = (_Float16)s;
            }
            // B fragment: bit -> f16 1.0 via spread-multiply (0x10001 * 0x3C00 = 0x3C003C00)
            union { half8 h; uint32_t w4[4]; } bfu;
            uint32_t xb = byte | (byte << 15);
            bfu.w4[0] = ((xb >> 0) & 0x10001u) * 0x3C00u;
            bfu.w4[1] = ((xb >> 2) & 0x10001u) * 0x3C00u;
            bfu.w4[2] = ((xb >> 4) & 0x10001u) * 0x3C00u;
            bfu.w4[3] = ((xb >> 6) & 0x10001u) * 0x3C00u;

            if (grp & 1) acc1 = __builtin_amdgcn_mfma_f32_16x16x32_f16(af, bfu.h, acc1, 0, 0, 0);
            else         acc0 = __builtin_amdgcn_mfma_f32_16x16x32_f16(af, bfu.h, acc0, 0, 0, 0);
        }

        __syncthreads();                 // done reading tile; reuse as reduction buffer
        float* red = (float*)tile;       // [4][16][17]
        #pragma unroll
        for (int j = 0; j < 4; ++j)
            red[(w * 16 + pq * 4 + j) * 17 + mn] = acc0[j] + acc1[j];
        __syncthreads();
        {
            int row = tid >> 4, g = tid & 15;
            float v = red[(0 * 16 + row) * 17 + g] + red[(1 * 16 + row) * 17 + g]
                    + red[(2 * 16 + row) * 17 + g] + red[(3 * 16 + row) * 17 + g];
            int gq = qbase + row;
            if (gq < Q_)
                atomicAdd(&out[gq * G_ + g], v * (0.5f / (float)cntS[g]));
        }
    } else {
        // ================= dice + class (wave per (q,g)) =================
        int w = tid >> 6;
        int l = tid & 63;
        int pr = (bid - 896) * 4 + w;
        int q = pr >> 4;
        int g = pr & 15;

        // softmax over 81 logits
        float v0 = (l < C_) ? logits[q * C_ + l] : -1e30f;
        float v1 = (l + 64 < C_) ? logits[q * C_ + l + 64] : -1e30f;
        float mx = fmaxf(v0, v1);
        #pragma unroll
        for (int o = 32; o > 0; o >>= 1) mx = fmaxf(mx, __shfl_xor(mx, o, 64));
        float es = ((l < C_) ? __expf(v0 - mx) : 0.0f)
                 + ((l + 64 < C_) ? __expf(v1 - mx) : 0.0f);
        #pragma unroll
        for (int o = 32; o > 0; o >>= 1) es += __shfl_xor(es, o, 64);

        float d3 = 0, t3 = 0, s3 = 0, d2 = 0, t2 = 0, s2 = 0;
        #pragma unroll
        for (int i = 0; i < 4; ++i) {
            int c = i * 64 + l;          // (t,pos) flattened over 256
            int tt = c >> 7, cc = c & 127;
            float sW = sig_(srcMW[(q * 2 + tt) * 128 + cc]);
            float mh = srcMHp[((q * 2 + tt) * 4 + 0) * 128 + cc];
            #pragma unroll
            for (int r = 1; r < 4; ++r)
                mh = fmaxf(mh, srcMHp[((q * 2 + tt) * 4 + r) * 128 + cc]);
            float sH = sig_(mh);
            float tW = (float)tgtMWi[(g * 2 + tt) * 128 + cc];
            int th = tgtMHp[((g * 2 + tt) * 8 + 0) * 128 + cc];
            #pragma unroll
            for (int r = 1; r < 8; ++r)
                th = max(th, tgtMHp[((g * 2 + tt) * 8 + r) * 128 + cc]);
            float tH = (float)th;
            d3 += sW * tW; t3 += tW; s3 += sW;
            d2 += sH * tH; t2 += tH; s2 += sH;
        }
        #pragma unroll
        for (int o = 32; o > 0; o >>= 1) {
            d3 += __shfl_xor(d3, o, 64); t3 += __shfl_xor(t3, o, 64);
            s3 += __shfl_xor(s3, o, 64); d2 += __shfl_xor(d2, o, 64);
            t2 += __shfl_xor(t2, o, 64); s2 += __shfl_xor(s2, o, 64);
        }
        if (l == 0) {
            float p = __expf(logits[q * C_ + ids[g]] - mx) / es;
            float dice3 = 1.0f - (2.0f * d3 + 1.0f) / (s3 + t3 + 1.0f);
            float dice2 = 1.0f - (2.0f * d2 + 1.0f) / (s2 + t2 + 1.0f);
            atomicAdd(&out[q * G_ + g], -p + dice3 + dice2);
        }
    }
}

extern "C" void kernel_launch(void* const* d_in, const int* in_sizes, int n_in,
                              void* d_out, int out_size, void* d_ws, size_t ws_size,
                              hipStream_t stream) {
    const float* pred_logits = (const float*)d_in[0];
    const float* out_mask    = (const float*)d_in[1];
    const float* sims        = (const float*)d_in[2];
    const int*   tgt_ids     = (const int*)d_in[3];
    const int*   tgt_box     = (const int*)d_in[4];
    float* out = (float*)d_out;

    // workspace layout (u32 units)
    float*    srcMW    = (float*)d_ws;                       // 25600
    float*    srcMHp   = srcMW + Q_ * T_ * 128;              // 102400
    int*      tgtMWi   = (int*)(srcMHp + Q_ * T_ * 4 * 128); // 4096
    int*      tgtMHp   = tgtMWi + G_ * T_ * 128;             // 32768
    int*      cnt_part = tgtMHp + G_ * T_ * 8 * 128;         // 1024
    uint32_t* packed   = (uint32_t*)(cnt_part + 64 * 16);    // 131072 (16B-aligned)

    k_prep<<<1313, 256, 0, stream>>>(out_mask, tgt_box, sims,
                                     srcMW, srcMHp, tgtMWi, tgtMHp, packed, cnt_part, out);
    k_main<<<1296, 256, 0, stream>>>(out_mask, packed, cnt_part, pred_logits, tgt_ids,
                                     srcMW, srcMHp, tgtMWi, tgtMHp, out);
}

// Round 12
// 109.455 us; speedup vs baseline: 2.4176x; 1.0068x over previous
//
#include <hip/hip_runtime.h>
#include <hip/hip_fp16.h>
#include <cstdint>

#define Q_ 100
#define G_ 16
#define T_ 2
#define H_ 128
#define W_ 128
#define HW_ (H_*W_)
#define C_ 81
#define RS_ 69            // tile row stride (u32 words), == 5 mod 32
#define QS_ 553           // tile q stride = 8*69+1, == 9 mod 32

typedef _Float16 half8 __attribute__((ext_vector_type(8)));
typedef float floatx4 __attribute__((ext_vector_type(4)));

__device__ __forceinline__ float sig_(float x) { return 1.0f / (1.0f + __expf(-x)); }

// ---------------- fused prep ----------------
// blocks 0..799  srcmax (qt, 32-row group)
// blocks 800..1055 tgtmax (gt, 16-row group)
// blocks 1056..1311 pack (512 px, one gg)
// block 1312 zero out[Q*G]
__launch_bounds__(256)
__global__ void k_prep(const float* __restrict__ om,
                       const int* __restrict__ box,
                       const float* __restrict__ sims,
                       float* __restrict__ srcMW,     // (QT,128) row-max
                       float* __restrict__ srcMHp,    // (QT,4,128) col-max partials
                       int* __restrict__ tgtMWi,      // (GT,128) row-max
                       int* __restrict__ tgtMHp,      // (GT,8,128) col-max partials
                       uint32_t* __restrict__ packed, // [4][T*HW]
                       int* __restrict__ cnt_part,    // [64 pxblk][16 g]
                       float* __restrict__ out) {     // zeroed by last block
    __shared__ float credF[128];
    __shared__ int redI[4][4];
    int bid = blockIdx.x;
    int tid = threadIdx.x;

    if (bid < 800) {
        // ---- srcmax ----
        int qt = bid >> 2;
        int rg = bid & 3;
        const float* base = om + (size_t)qt * HW_ + rg * 32 * W_;
        {
            int r = tid >> 3, seg = tid & 7;
            const float4* rp = (const float4*)(base + r * W_ + seg * 16);
            float m = -1e30f;
            #pragma unroll
            for (int i = 0; i < 4; ++i) {
                float4 v = rp[i];
                m = fmaxf(m, fmaxf(fmaxf(v.x, v.y), fmaxf(v.z, v.w)));
            }
            m = fmaxf(m, __shfl_xor(m, 1, 64));
            m = fmaxf(m, __shfl_xor(m, 2, 64));
            m = fmaxf(m, __shfl_xor(m, 4, 64));
            if (seg == 0) srcMW[qt * 128 + rg * 32 + r] = m;
        }
        {
            int c = tid & 127, rh = tid >> 7;
            const float* cp = base + rh * 16 * W_ + c;
            float m = -1e30f;
            #pragma unroll
            for (int i = 0; i < 16; ++i) m = fmaxf(m, cp[i * W_]);
            if (rh == 1) credF[c] = m;
            __syncthreads();
            if (rh == 0) srcMHp[(qt * 4 + rg) * 128 + c] = fmaxf(m, credF[c]);
        }
    } else if (bid < 1056) {
        // ---- tgtmax ----
        int b2 = bid - 800;
        int gt = b2 >> 3;
        int rg = b2 & 7;
        const int* base = box + (size_t)gt * HW_ + rg * 16 * W_;
        {
            int r = tid >> 4, seg = tid & 15;
            const int4* rp = (const int4*)(base + r * W_ + seg * 8);
            int4 a = rp[0], b = rp[1];
            int m = max(max(max(a.x, a.y), max(a.z, a.w)),
                        max(max(b.x, b.y), max(b.z, b.w)));
            m = max(m, __shfl_xor(m, 1, 64));
            m = max(m, __shfl_xor(m, 2, 64));
            m = max(m, __shfl_xor(m, 4, 64));
            m = max(m, __shfl_xor(m, 8, 64));
            if (seg == 0) tgtMWi[gt * 128 + rg * 16 + r] = m;
        }
        {
            int* credi = (int*)credF;
            int c = tid & 127, rh = tid >> 7;
            const int* cp = base + rh * 8 * W_ + c;
            int m = 0;
            #pragma unroll
            for (int i = 0; i < 8; ++i) m = max(m, cp[i * W_]);
            if (rh == 1) credi[c] = m;
            __syncthreads();
            if (rh == 0) tgtMHp[(gt * 8 + rg) * 128 + c] = max(m, credi[c]);
        }
    } else if (bid < 1312) {
        // ---- pack ----
        int b3 = bid - 1056;
        int gg = b3 & 3;
        int pxblk = b3 >> 2;
        int p0 = pxblk * 512 + tid * 2;
        int t = p0 >> 14;
        int pp = p0 & (HW_ - 1);

        uint32_t w0 = 0, w1 = 0;
        int pc[4];
        #pragma unroll
        for (int b = 0; b < 4; ++b) {
            int g = gg * 4 + b;
            const float* sbase = sims + ((size_t)(g * T_ + t) * 8) * HW_ + pp;
            int2 bx = *(const int2*)(box + (size_t)(g * T_ + t) * HW_ + pp);
            uint32_t by0 = 0, by1 = 0;
            #pragma unroll
            for (int e = 0; e < 8; ++e) {
                float2 sv = *(const float2*)(sbase + (size_t)e * HW_);
                by0 |= (sv.x >= 0.3f ? 1u : 0u) << e;
                by1 |= (sv.y >= 0.3f ? 1u : 0u) << e;
            }
            by0 = bx.x ? by0 : 0u;
            by1 = bx.y ? by1 : 0u;
            w0 |= by0 << (b * 8);
            w1 |= by1 << (b * 8);
            pc[b] = __popc(by0) + __popc(by1);
        }
        *(uint2*)&packed[(size_t)gg * (T_ * HW_) + p0] = make_uint2(w0, w1);

        int wid = tid >> 6, lane = tid & 63;
        #pragma unroll
        for (int b = 0; b < 4; ++b) {
            int s = pc[b];
            #pragma unroll
            for (int o = 32; o > 0; o >>= 1) s += __shfl_down(s, o, 64);
            if (lane == 0) redI[wid][b] = s;
        }
        __syncthreads();
        if (tid < 4)
            cnt_part[pxblk * 16 + gg * 4 + tid] =
                redI[0][tid] + redI[1][tid] + redI[2][tid] + redI[3][tid];
    } else {
        // ---- zero out (Q*G = 1600 floats) ----
        #pragma unroll
        for (int i = 0; i < 7; ++i) {
            int idx = i * 256 + tid;
            if (idx < Q_ * G_) out[idx] = 0.0f;
        }
    }
}

// ---------------- fused main: pair (blocks 0..895) + dice/class (blocks 896..1295) ----------------
// pair block: 16 q x 4 rows x 64 cols. Lane (mn = l&15, pq = l>>4); wave w = row.
// Inner loop: 3-row x 12-col register window per half-pass (72 ds_read_b32/lane-iter vs 144).
// Bank map per fixed tap: (9*mn + 16*pq) mod 32 = exactly 2-way (free).
// s = Lp + Ln - log(1 + Ep*En), (E,L) = (exp(-x), softplus(-x)) staged as half2.
__launch_bounds__(256, 4)
__global__ void k_main(const float* __restrict__ om,
                       const uint32_t* __restrict__ packed,  // [4][T*HW]
                       const int* __restrict__ cnt_part,     // [64][16]
                       const float* __restrict__ logits, const int* __restrict__ ids,
                       const float* __restrict__ srcMW, const float* __restrict__ srcMHp,
                       const int* __restrict__ tgtMWi, const int* __restrict__ tgtMHp,
                       float* __restrict__ out) {
    __shared__ uint32_t tile[16 * QS_];   // pair: staged (E,L); reused as f32 reduction buf
    __shared__ int cntS[16];
    int bid = blockIdx.x;
    int tid = threadIdx.x;

    if (bid < 896) {
        // ================= pair =================
        int wh = bid & 1;
        int rg = (bid >> 1) & 31;
        int t  = (bid >> 6) & 1;
        int qt = bid >> 7;
        int qbase = qt * 16;
        int rowbase = rg * 4;
        int cbase = wh * 64;

        // main strip: cols cbase..cbase+63 (aligned float4) -> tile cols 2..65
        #pragma unroll
        for (int i = 0; i < 8; ++i) {
            int idx = i * 256 + tid;
            int c4 = idx & 15;
            int row = (idx >> 4) & 7;
            int q = idx >> 7;
            int gq = qbase + q;
            int grow = rowbase - 2 + row;
            float4 x = make_float4(0.f, 0.f, 0.f, 0.f);
            if (gq < Q_ && (unsigned)grow < (unsigned)H_)
                x = *(const float4*)(om + (((size_t)gq * T_ + t) * H_ + grow) * W_ + cbase + c4 * 4);
            uint32_t* dst = &tile[q * QS_ + row * RS_ + 2 + c4 * 4];
            {
                float E = __expf(-x.x); __half2 h = __floats2half2_rn(E, __logf(1.f + E)); dst[0] = *(uint32_t*)&h;
            }{
                float E = __expf(-x.y); __half2 h = __floats2half2_rn(E, __logf(1.f + E)); dst[1] = *(uint32_t*)&h;
            }{
                float E = __expf(-x.z); __half2 h = __floats2half2_rn(E, __logf(1.f + E)); dst[2] = *(uint32_t*)&h;
            }{
                float E = __expf(-x.w); __half2 h = __floats2half2_rn(E, __logf(1.f + E)); dst[3] = *(uint32_t*)&h;
            }
        }
        // tail strip: tile cols {0,1,66,67} (gcol cbase-2,-1,+64,+65)
        #pragma unroll
        for (int i = 0; i < 2; ++i) {
            int idx = i * 256 + tid;
            int cc = idx & 3;
            int row = (idx >> 2) & 7;
            int q = idx >> 5;
            int col = (cc < 2) ? cc : cc + 64;
            int gcol = cbase - 2 + col;
            int gq = qbase + q;
            int grow = rowbase - 2 + row;
            float x = 0.f;
            if (gq < Q_ && (unsigned)grow < (unsigned)H_ && (unsigned)gcol < (unsigned)W_)
                x = om[(((size_t)gq * T_ + t) * H_ + grow) * W_ + gcol];
            float E = __expf(-x);
            __half2 h = __floats2half2_rn(E, __logf(1.f + E));
            tile[q * QS_ + row * RS_ + col] = *(uint32_t*)&h;
        }
        // per-block denominator self-reduction (overlaps staging latency)
        if (tid < 16) {
            int s = 0;
            #pragma unroll
            for (int i = 0; i < 32; ++i) s += cnt_part[(t * 32 + i) * 16 + tid];
            cntS[tid] = max(1, s);
        }
        __syncthreads();

        int l = tid & 63;
        int w = tid >> 6;
        int mn = l & 15;
        int pq = l >> 4;
        int growS = rowbase + w;

        // preload this lane's 16 packed words (cols pq*16..pq*16+15) of its gg plane
        const uint32_t* pbase = packed + (size_t)(mn >> 2) * (T_ * HW_) + t * HW_
                              + (growS << 7) + cbase + (pq << 4);
        uint4 pkA = *(const uint4*)(pbase + 0);
        uint4 pkB = *(const uint4*)(pbase + 4);
        uint4 pkC = *(const uint4*)(pbase + 8);
        uint4 pkD = *(const uint4*)(pbase + 12);
        uint32_t pkw[16] = {pkA.x, pkA.y, pkA.z, pkA.w, pkB.x, pkB.y, pkB.z, pkB.w,
                            pkC.x, pkC.y, pkC.z, pkC.w, pkD.x, pkD.y, pkD.z, pkD.w};

        const uint32_t* tqw = &tile[mn * QS_ + (w + 2) * RS_ + 2 + (pq << 4)];

        bool rowU = (growS >= 2), rowD = (growS <= H_ - 3);
        int bsh = (mn & 3) * 8;

        floatx4 acc0 = {0.f,0.f,0.f,0.f}, acc1 = {0.f,0.f,0.f,0.f};

        #pragma unroll
        for (int hp = 0; hp < 2; ++hp) {
            // register window: rows {-2,0,+2} x cols [hp*8-2 .. hp*8+9]
            uint32_t R[3][12];
            #pragma unroll
            for (int c = 0; c < 12; ++c) {
                int off = hp * 8 - 2 + c;
                R[0][c] = tqw[off - 2 * RS_];
                R[1][c] = tqw[off];
                R[2][c] = tqw[off + 2 * RS_];
            }
            #pragma unroll
            for (int g = 0; g < 8; ++g) {
                int grp = hp * 8 + g;
                int gcol = cbase + (pq << 4) + grp;
                bool colL = (gcol >= 2), colR = (gcol <= W_ - 3);
                bool m8[8] = {rowU && colL, rowU, rowU && colR,
                              colL, colR,
                              rowD && colL, rowD, rowD && colR};
                // taps: e0..e2 row0 cols {g,g+2,g+4}; e3,e4 row1 {g,g+4}; e5..e7 row2 {g,g+2,g+4}
                uint32_t nbr[8] = {R[0][g], R[0][g + 2], R[0][g + 4],
                                   R[1][g],             R[1][g + 4],
                                   R[2][g], R[2][g + 2], R[2][g + 4]};

                uint32_t selfw = R[1][g + 2];
                __half2 sh = *(__half2*)&selfw;
                float Ep = __half2float(__low2half(sh));
                float Lp = __half2float(__high2half(sh));
                uint32_t byte = (pkw[grp] >> bsh) & 255u;

                half8 af;
                #pragma unroll
                for (int e = 0; e < 8; ++e) {
                    uint32_t nw = nbr[e];
                    __half2 nh = *(__half2*)&nw;
                    float En = __half2float(__low2half(nh));
                    float Ln = __half2float(__high2half(nh));
                    float s = Lp + Ln - __logf(fmaf(Ep, En, 1.0f));
                    s = m8[e] ? s : 0.0f;
                    af[e] = (_Float16)s;
                }
                // B fragment: bit -> f16 1.0 via spread-multiply (0x10001 * 0x3C00 = 0x3C003C00)
                union { half8 h; uint32_t w4[4]; } bfu;
                uint32_t xb = byte | (byte << 15);
                bfu.w4[0] = ((xb >> 0) & 0x10001u) * 0x3C00u;
                bfu.w4[1] = ((xb >> 2) & 0x10001u) * 0x3C00u;
                bfu.w4[2] = ((xb >> 4) & 0x10001u) * 0x3C00u;
                bfu.w4[3] = ((xb >> 6) & 0x10001u) * 0x3C00u;

                if (grp & 1) acc1 = __builtin_amdgcn_mfma_f32_16x16x32_f16(af, bfu.h, acc1, 0, 0, 0);
                else         acc0 = __builtin_amdgcn_mfma_f32_16x16x32_f16(af, bfu.h, acc0, 0, 0, 0);
            }
        }

        __syncthreads();                 // done reading tile; reuse as reduction buffer
        float* red = (float*)tile;       // [4][16][17]
        #pragma unroll
        for (int j = 0; j < 4; ++j)
            red[(w * 16 + pq * 4 + j) * 17 + mn] = acc0[j] + acc1[j];
        __syncthreads();
        {
            int row = tid >> 4, g = tid & 15;
            float v = red[(0 * 16 + row) * 17 + g] + red[(1 * 16 + row) * 17 + g]
                    + red[(2 * 16 + row) * 17 + g] + red[(3 * 16 + row) * 17 + g];
            int gq = qbase + row;
            if (gq < Q_)
                atomicAdd(&out[gq * G_ + g], v * (0.5f / (float)cntS[g]));
        }
    } else {
        // ================= dice + class (wave per (q,g)) =================
        int w = tid >> 6;
        int l = tid & 63;
        int pr = (bid - 896) * 4 + w;
        int q = pr >> 4;
        int g = pr & 15;

        // softmax over 81 logits
        float v0 = (l < C_) ? logits[q * C_ + l] : -1e30f;
        float v1 = (l + 64 < C_) ? logits[q * C_ + l + 64] : -1e30f;
        float mx = fmaxf(v0, v1);
        #pragma unroll
        for (int o = 32; o > 0; o >>= 1) mx = fmaxf(mx, __shfl_xor(mx, o, 64));
        float es = ((l < C_) ? __expf(v0 - mx) : 0.0f)
                 + ((l + 64 < C_) ? __expf(v1 - mx) : 0.0f);
        #pragma unroll
        for (int o = 32; o > 0; o >>= 1) es += __shfl_xor(es, o, 64);

        float d3 = 0, t3 = 0, s3 = 0, d2 = 0, t2 = 0, s2 = 0;
        #pragma unroll
        for (int i = 0; i < 4; ++i) {
            int c = i * 64 + l;          // (t,pos) flattened over 256
            int tt = c >> 7, cc = c & 127;
            float sW = sig_(srcMW[(q * 2 + tt) * 128 + cc]);
            float mh = srcMHp[((q * 2 + tt) * 4 + 0) * 128 + cc];
            #pragma unroll
            for (int r = 1; r < 4; ++r)
                mh = fmaxf(mh, srcMHp[((q * 2 + tt) * 4 + r) * 128 + cc]);
            float sH = sig_(mh);
            float tW = (float)tgtMWi[(g * 2 + tt) * 128 + cc];
            int th = tgtMHp[((g * 2 + tt) * 8 + 0) * 128 + cc];
            #pragma unroll
            for (int r = 1; r < 8; ++r)
                th = max(th, tgtMHp[((g * 2 + tt) * 8 + r) * 128 + cc]);
            float tH = (float)th;
            d3 += sW * tW; t3 += tW; s3 += sW;
            d2 += sH * tH; t2 += tH; s2 += sH;
        }
        #pragma unroll
        for (int o = 32; o > 0; o >>= 1) {
            d3 += __shfl_xor(d3, o, 64); t3 += __shfl_xor(t3, o, 64);
            s3 += __shfl_xor(s3, o, 64); d2 += __shfl_xor(d2, o, 64);
            t2 += __shfl_xor(t2, o, 64); s2 += __shfl_xor(s2, o, 64);
        }
        if (l == 0) {
            float p = __expf(logits[q * C_ + ids[g]] - mx) / es;
            float dice3 = 1.0f - (2.0f * d3 + 1.0f) / (s3 + t3 + 1.0f);
            float dice2 = 1.0f - (2.0f * d2 + 1.0f) / (s2 + t2 + 1.0f);
            atomicAdd(&out[q * G_ + g], -p + dice3 + dice2);
        }
    }
}

extern "C" void kernel_launch(void* const* d_in, const int* in_sizes, int n_in,
                              void* d_out, int out_size, void* d_ws, size_t ws_size,
                              hipStream_t stream) {
    const float* pred_logits = (const float*)d_in[0];
    const float* out_mask    = (const float*)d_in[1];
    const float* sims        = (const float*)d_in[2];
    const int*   tgt_ids     = (const int*)d_in[3];
    const int*   tgt_box     = (const int*)d_in[4];
    float* out = (float*)d_out;

    // workspace layout (u32 units)
    float*    srcMW    = (float*)d_ws;                       // 25600
    float*    srcMHp   = srcMW + Q_ * T_ * 128;              // 102400
    int*      tgtMWi   = (int*)(srcMHp + Q_ * T_ * 4 * 128); // 4096
    int*      tgtMHp   = tgtMWi + G_ * T_ * 128;             // 32768
    int*      cnt_part = tgtMHp + G_ * T_ * 8 * 128;         // 1024
    uint32_t* packed   = (uint32_t*)(cnt_part + 64 * 16);    // 131072 (16B-aligned)

    k_prep<<<1313, 256, 0, stream>>>(out_mask, tgt_box, sims,
                                     srcMW, srcMHp, tgtMWi, tgtMHp, packed, cnt_part, out);
    k_main<<<1296, 256, 0, stream>>>(out_mask, packed, cnt_part, pred_logits, tgt_ids,
                                     srcMW, srcMHp, tgtMWi, tgtMHp, out);
}